// Round 12
// baseline (251.612 us; speedup 1.0000x reference)
//
#include <hip/hip_runtime.h>

namespace {

typedef _Float16 half_t;
typedef half_t f16x2 __attribute__((ext_vector_type(2)));
typedef half_t f16x8 __attribute__((ext_vector_type(8)));
typedef float f32x4 __attribute__((ext_vector_type(4)));

constexpr size_t RSTR = 64 * 64 * 32;  // s1 stride in floats

// ---- ws layout (f16 element offsets), all arrays are [frag][lane][8] packed ----
constexpr int WS_TF = 0;       // forward Tf frags: 4  (mt*2+kt)
constexpr int WS_TI = 2048;    // inverse Ti frags: 4  (mt)
constexpr int WS_WZ = 4096;    // mix W' z-branch: 16 modes x 8 (kt*4+nt)
constexpr int WS_WX = 69632;   // mix W' x-branch
constexpr int WS_W1 = 135168;  // FFN w1 frags: 4 (nt)
constexpr int WS_W2 = 137216;  // FFN w2 frags: 4 (kt*2+nt)

__device__ __forceinline__ float f4get(const float4& v, int u) {
  return u == 0 ? v.x : (u == 1 ? v.y : (u == 2 ? v.z : v.w));
}

__device__ __forceinline__ f32x4 mfma16(f16x8 a, f16x8 b, f32x4 c) {
  return __builtin_amdgcn_mfma_f32_16x16x32_f16(a, b, c, 0, 0, 0);
}

// Pre-pack all shared MFMA operands into ws, fragment-ordered per lane.
//   lane l: r=l&15, g=l>>4; element e of K-tile kt -> k = kt*32 + 8*g + e
//   A[row=Mtile*16+r][k]; B[k][col=Ntile*16+r]
__global__ __launch_bounds__(256) void kinit(const float* __restrict__ wx,
                                             const float* __restrict__ wz,
                                             const float* __restrict__ w1,
                                             const float* __restrict__ w2,
                                             half_t* __restrict__ wsh) {
  const int id = blockIdx.x * 256 + threadIdx.x;
  const int l = id & 63, r = l & 15, g = l >> 4;
  f16x8 frag;
  if (id < 256) {  // Tf: [mc=2m+p][z], 1/8 norm, -sin folded
    int fid = id >> 6, mt = fid >> 1, kt = fid & 1;
#pragma unroll
    for (int e = 0; e < 8; ++e) {
      int k = kt * 32 + 8 * g + e;  // z
      int mc = mt * 16 + r, m = mc >> 1, p = mc & 1;
      float s, c;
      sincospif((float)(m * k) * (1.0f / 32.0f), &s, &c);
      frag[e] = (half_t)(0.125f * (p ? -s : c));
    }
    *(f16x8*)(wsh + WS_TF + (size_t)id * 8) = frag;
  } else if (id < 512) {  // Ti: [z'][k=2m+p], sc_0=1/8 else 1/4, (cos, -sin)
    int id2 = id - 256, mt = id2 >> 6;
#pragma unroll
    for (int e = 0; e < 8; ++e) {
      int zp = mt * 16 + r;
      int k = 8 * g + e, m = k >> 1, p = k & 1;
      float s, c;
      sincospif((float)(m * zp) * (1.0f / 32.0f), &s, &c);
      float sc = (m == 0) ? 0.125f : 0.25f;
      frag[e] = (half_t)(p ? -sc * s : sc * c);
    }
    *(f16x8*)(wsh + WS_TI + (size_t)id2 * 8) = frag;
  } else if (id < 16896) {  // W' realified: [k=2i+p][n=2o+q] per mode
    int id2 = id - 512;
    const float* wsrc = wz;
    size_t off = WS_WZ;
    if (id2 >= 8192) { id2 -= 8192; wsrc = wx; off = WS_WX; }
    int fid = id2 >> 6, m = fid >> 3, kt = (fid >> 2) & 1, nt = fid & 3;
#pragma unroll
    for (int e = 0; e < 8; ++e) {
      int k = kt * 32 + 8 * g + e, i = k >> 1, p = k & 1;
      int n = nt * 16 + r, o = n >> 1, q = n & 1;
      int base = ((i * 32 + o) * 16 + m) * 2;  // raw [i][o][mode][2]
      float re = wsrc[base], im = wsrc[base + 1];
      frag[e] = (half_t)(q ? (p ? re : im) : (p ? -im : re));
    }
    *(f16x8*)(wsh + off + (size_t)id2 * 8) = frag;
  } else if (id < 17152) {  // w1 [32 k][64 n]
    int id2 = id - 16896, nt = id2 >> 6;
#pragma unroll
    for (int e = 0; e < 8; ++e) {
      int k = 8 * g + e, n = nt * 16 + r;
      frag[e] = (half_t)w1[k * 64 + n];
    }
    *(f16x8*)(wsh + WS_W1 + (size_t)id2 * 8) = frag;
  } else if (id < 17408) {  // w2 [64 k][32 n]
    int id2 = id - 17152, fid = id2 >> 6, kt = fid >> 1, nt = fid & 1;
#pragma unroll
    for (int e = 0; e < 8; ++e) {
      int k = kt * 32 + 8 * g + e, n = nt * 16 + r;
      frag[e] = (half_t)w2[k * 32 + n];
    }
    *(f16x8*)(wsh + WS_W2 + (size_t)id2 * 8) = frag;
  }
}

// ============== z-branch (unchanged: ~BW-bound at 6.3 TB/s) ==============
template <int BR>
__global__ __launch_bounds__(256) void kspec(const float* __restrict__ x,
                                             const half_t* __restrict__ wsh,
                                             const float* __restrict__ b1g,
                                             const float* __restrict__ b2g,
                                             float* __restrict__ outf) {
  __shared__ __align__(16) char smraw[49152];
  half_t* XB = (half_t*)smraw;            // [256 rows=(c,i)][64 z] swz
  half_t* FB = (half_t*)smraw;            // [16 m][16 c][64 k=2i+p] swz
  half_t* PB = (half_t*)(smraw + 32768);  // [8 c][32 o][32 k=2m+p] swz
  half_t* outh = (half_t*)outf;
  const int t = threadIdx.x, l = t & 63, w = t >> 6, r = l & 15, g = l >> 4;
  const f32x4 vzero = {0.f, 0.f, 0.f, 0.f};

  const int col0 = blockIdx.x * 8;
  size_t xbase = (size_t)col0 * 2048, zstr = 32, cstr = 2048;

  {  // stage x -> XB
    int c = t >> 5, sub = t & 31;
    int i4 = (sub & 7) * 4, zq = sub >> 3;
    const float* xp = x + xbase + (size_t)c * cstr + i4;
#pragma unroll
    for (int zo = 0; zo < 2; ++zo) {
      int zb = zq * 16 + zo * 8;
      float4 v[8];
#pragma unroll
      for (int zz = 0; zz < 8; ++zz)
        v[zz] = *(const float4*)(xp + (size_t)(zb + zz) * zstr);
#pragma unroll
      for (int u = 0; u < 4; ++u) {
        f16x8 rowv;
#pragma unroll
        for (int zz = 0; zz < 8; ++zz) rowv[zz] = (half_t)f4get(v[zz], u);
        int rowi = c * 32 + i4 + u;
        int gr = (zb >> 3) ^ (rowi & 7);
        *(f16x8*)(XB + rowi * 64 + gr * 8) = rowv;
      }
    }
  }
  __syncthreads();

  // forward
  f32x4 fa[2][4];
#pragma unroll
  for (int mt = 0; mt < 2; ++mt)
#pragma unroll
    for (int nt = 0; nt < 4; ++nt) fa[mt][nt] = vzero;
  {
    f16x8 Atf[2][2], Bx[4][2];
#pragma unroll
    for (int mt = 0; mt < 2; ++mt)
#pragma unroll
      for (int kt = 0; kt < 2; ++kt)
        Atf[mt][kt] = *(const f16x8*)(wsh + WS_TF + (size_t)((mt * 2 + kt) * 64 + l) * 8);
#pragma unroll
    for (int nt = 0; nt < 4; ++nt)
#pragma unroll
      for (int kt = 0; kt < 2; ++kt) {
        int rowi = w * 64 + nt * 16 + r;
        int gr = (kt * 4 + g) ^ (rowi & 7);
        Bx[nt][kt] = *(const f16x8*)(XB + rowi * 64 + gr * 8);
      }
#pragma unroll
    for (int kt = 0; kt < 2; ++kt)
#pragma unroll
      for (int nt = 0; nt < 4; ++nt)
#pragma unroll
        for (int mt = 0; mt < 2; ++mt)
          fa[mt][nt] = mfma16(Atf[mt][kt], Bx[nt][kt], fa[mt][nt]);
  }
  __syncthreads();

#pragma unroll
  for (int mt = 0; mt < 2; ++mt)
#pragma unroll
    for (int nt = 0; nt < 4; ++nt)
#pragma unroll
      for (int q = 0; q < 4; ++q) {
        int mc = mt * 16 + 4 * g + q, m = mc >> 1, p = mc & 1;
        int n = w * 64 + nt * 16 + r, c = n >> 5, i = n & 31;
        int k = 2 * i + p;
        FB[(m * 16 + c) * 64 + ((k >> 3) ^ (c & 7)) * 8 + (k & 7)] = (half_t)fa[mt][nt][q];
      }
  __syncthreads();

  // mix
  const half_t* WF = wsh + WS_WZ;
#pragma unroll
  for (int j = 0; j < 4; ++j) {
    int m = w * 4 + j;
    f16x8 Af[2];
#pragma unroll
    for (int kt = 0; kt < 2; ++kt) {
      int gr = (kt * 4 + g) ^ (r & 7);
      Af[kt] = *(const f16x8*)(FB + (m * 16 + r) * 64 + gr * 8);
    }
    f32x4 pa[4];
#pragma unroll
    for (int nt = 0; nt < 4; ++nt) pa[nt] = vzero;
#pragma unroll
    for (int kt = 0; kt < 2; ++kt)
#pragma unroll
      for (int nt = 0; nt < 4; ++nt) {
        f16x8 Bw = *(const f16x8*)(WF + (size_t)((m * 8 + kt * 4 + nt) * 64 + l) * 8);
        pa[nt] = mfma16(Af[kt], Bw, pa[nt]);
      }
#pragma unroll
    for (int nt = 0; nt < 4; ++nt)
#pragma unroll
      for (int q = 0; q < 4; ++q) {
        int c = 4 * g + q;
        if (c < 8) {
          int n = nt * 16 + r, o = n >> 1, q2 = n & 1;
          int k = 2 * m + q2;
          PB[(c * 32 + o) * 32 + ((k >> 3) ^ (o & 3)) * 8 + (k & 7)] = (half_t)pa[nt][q];
        }
      }
  }
  __syncthreads();

  // inverse + store y_z f16 into out scratch slots
  {
    f16x8 Ati[4];
#pragma unroll
    for (int mt = 0; mt < 4; ++mt)
      Ati[mt] = *(const f16x8*)(wsh + WS_TI + (size_t)(mt * 64 + l) * 8);
#pragma unroll
    for (int cc = 0; cc < 2; ++cc) {
      int c = w * 2 + cc;
      f16x8 Bp[2];
#pragma unroll
      for (int nt = 0; nt < 2; ++nt) {
        int o = nt * 16 + r;
        Bp[nt] = *(const f16x8*)(PB + (c * 32 + o) * 32 + (g ^ (o & 3)) * 8);
      }
      f32x4 ya[4][2];
#pragma unroll
      for (int mt = 0; mt < 4; ++mt)
#pragma unroll
        for (int nt = 0; nt < 2; ++nt) ya[mt][nt] = mfma16(Ati[mt], Bp[nt], vzero);
#pragma unroll
      for (int mt = 0; mt < 4; ++mt)
#pragma unroll
        for (int nt = 0; nt < 2; ++nt)
#pragma unroll
          for (int q = 0; q < 4; ++q) {
            int zp = mt * 16 + 4 * g + q, o = nt * 16 + r;
            outh[(size_t)(col0 + c) * 4096 + zp * 64 + o] = (half_t)ya[mt][nt][q];
          }
    }
  }
}

// ===== x-branch + FFN: 128-thread blocks, C=2, 16KB LDS -> ~10 blocks/CU =====
__global__ __launch_bounds__(128, 5) void kx2(const float* __restrict__ x,
                                              const half_t* __restrict__ wsh,
                                              const float* __restrict__ b1g,
                                              const float* __restrict__ b2g,
                                              float* __restrict__ outf) {
  __shared__ __align__(16) half_t smh[8192];  // 16 KB
  half_t* XB = smh;          // [64 rows=(c*32+i)][64 z]   8KB [0,4096)
  half_t* FB = smh + 4096;   // [16 m][2 c][64 k=2i+p]     4KB [4096,6144)
  half_t* PB = smh + 6144;   // [2 c][32 o][32 k=2m+p]     4KB [6144,8192)
  half_t* YL = smh;          // [128 rows=(c*64+zp)][32 o] 8KB overlays XB (dead)
  half_t* HL = smh + 4096;   // [64 rows][64 n]            8KB overlays FB+PB (dead)
  half_t* outh = (half_t*)outf;
  const int t = threadIdx.x, l = t & 63, w = t >> 6, r = l & 15, g = l >> 4;
  const f32x4 vzero = {0.f, 0.f, 0.f, 0.f};

  const int d = blockIdx.x;
  const int pp = (d & 7) * 1024 + (d >> 3);  // XCD-bijective (8192 = 8*1024)
  const int col0 = pp * 2;
  const int b = col0 >> 12, s2 = (col0 >> 6) & 63, s30 = col0 & 63;
  const size_t xbase = (size_t)b * 8388608 + (size_t)s2 * 2048 + (size_t)s30 * 32;

  {  // ---- stage x -> XB; bijective key (rowi^(rowi>>2))&7 on write AND read ----
    int sub = t & 15, zq = t >> 4;  // zq in [0,8)
    int c = sub >> 3, i4 = (sub & 7) * 4;
    const float* xp = x + xbase + (size_t)c * 32 + i4 + (size_t)(zq * 8) * RSTR;
    float4 v[8];
#pragma unroll
    for (int zz = 0; zz < 8; ++zz) v[zz] = *(const float4*)(xp + (size_t)zz * RSTR);
#pragma unroll
    for (int uu = 0; uu < 4; ++uu) {
      int u = (uu + sub) & 3;  // lane-rotated to spread banks
      f16x8 rowv;
#pragma unroll
      for (int zz = 0; zz < 8; ++zz) rowv[zz] = (half_t)f4get(v[zz], u);
      int rowi = c * 32 + i4 + u;
      int key = (rowi ^ (rowi >> 2)) & 7;
      *(f16x8*)(XB + rowi * 64 + (zq ^ key) * 8) = rowv;
    }
  }
  __syncthreads();  // bar1: XB ready

  // ---- forward: F[32 mc][64 n=(c,i)] = Tf @ X; wave w covers col c=w ----
  f32x4 fa[2][2];
  {
    f16x8 Atf[2][2], Bx[2][2];
#pragma unroll
    for (int mt = 0; mt < 2; ++mt)
#pragma unroll
      for (int kt = 0; kt < 2; ++kt)
        Atf[mt][kt] = *(const f16x8*)(wsh + WS_TF + (size_t)((mt * 2 + kt) * 64 + l) * 8);
#pragma unroll
    for (int nt = 0; nt < 2; ++nt)
#pragma unroll
      for (int kt = 0; kt < 2; ++kt) {
        int rowi = w * 32 + nt * 16 + r;
        int key = (rowi ^ (rowi >> 2)) & 7;
        Bx[nt][kt] = *(const f16x8*)(XB + rowi * 64 + (((kt * 4 + g) ^ key)) * 8);
      }
#pragma unroll
    for (int mt = 0; mt < 2; ++mt)
#pragma unroll
      for (int nt = 0; nt < 2; ++nt) fa[mt][nt] = vzero;
#pragma unroll
    for (int kt = 0; kt < 2; ++kt)
#pragma unroll
      for (int nt = 0; nt < 2; ++nt)
#pragma unroll
        for (int mt = 0; mt < 2; ++mt)
          fa[mt][nt] = mfma16(Atf[mt][kt], Bx[nt][kt], fa[mt][nt]);
  }
  // FB region disjoint from XB: no barrier before writing.
  // Paired writes: q=(0,1),(2,3) share m and map to adjacent k.
#pragma unroll
  for (int mt = 0; mt < 2; ++mt)
#pragma unroll
    for (int nt = 0; nt < 2; ++nt)
#pragma unroll
      for (int pr = 0; pr < 2; ++pr) {
        int q = 2 * pr;
        int mc = mt * 16 + 4 * g + q, m = mc >> 1;
        int n = w * 32 + nt * 16 + r, c = n >> 5, i = n & 31;
        int k = 2 * i;
        f16x2 pairv = {(half_t)fa[mt][nt][q], (half_t)fa[mt][nt][q + 1]};
        *(f16x2*)(FB + (m * 2 + c) * 64 + (((k >> 3) ^ ((m + 2 * c) & 7))) * 8 + (k & 7)) =
            pairv;
      }
  __syncthreads();  // bar2: FB ready

  // ---- mix: 8 modes per wave; A rows r -> F[m][r&1] (bcast) ----
#pragma unroll
  for (int j = 0; j < 8; ++j) {
    int m = w * 8 + j;
    int rsel = r & 1, keym = (m + 2 * rsel) & 7;
    f16x8 Af[2];
#pragma unroll
    for (int kt = 0; kt < 2; ++kt)
      Af[kt] = *(const f16x8*)(FB + (m * 2 + rsel) * 64 + (((kt * 4 + g) ^ keym)) * 8);
    f32x4 pa[4];
#pragma unroll
    for (int nt = 0; nt < 4; ++nt) pa[nt] = vzero;
#pragma unroll
    for (int kt = 0; kt < 2; ++kt)
#pragma unroll
      for (int nt = 0; nt < 4; ++nt) {
        f16x8 Bw = *(const f16x8*)(wsh + WS_WX + (size_t)((m * 8 + kt * 4 + nt) * 64 + l) * 8);
        pa[nt] = mfma16(Af[kt], Bw, pa[nt]);
      }
    if (g == 0) {  // D rows 0..1 = c
#pragma unroll
      for (int nt = 0; nt < 4; ++nt)
#pragma unroll
        for (int q = 0; q < 2; ++q) {
          int c = q;
          int n = nt * 16 + r, o = n >> 1, q2 = n & 1;
          int k = 2 * m + q2;
          PB[(c * 32 + o) * 32 + (((k >> 3) ^ (o & 3))) * 8 + (k & 7)] = (half_t)pa[nt][q];
        }
    }
  }
  __syncthreads();  // bar3: PB ready

  // ---- inverse (c = w): y_x = Ti @ P_c -> YL ----
  // Issue order (in-order vmcnt): Ati (consumed now) FIRST, then FFN prefetches
  // (yzf + W1F) that drain at bar4 under this phase's compute.
  f16x8 Ati[4];
#pragma unroll
  for (int mt = 0; mt < 4; ++mt)
    Ati[mt] = *(const f16x8*)(wsh + WS_TI + (size_t)(mt * 64 + l) * 8);
  f16x8 Bp[2];
#pragma unroll
  for (int nt = 0; nt < 2; ++nt) {
    int o = nt * 16 + r;
    Bp[nt] = *(const f16x8*)(PB + (w * 32 + o) * 32 + ((g ^ (o & 3))) * 8);
  }
  // y_z fragments for FFN: round rr handles col c=rr; zp = w*32+mt*16+r.
  f16x8 yzf[2][2];
#pragma unroll
  for (int rr = 0; rr < 2; ++rr)
#pragma unroll
    for (int mt = 0; mt < 2; ++mt) {
      int zp = w * 32 + mt * 16 + r;
      size_t col = (size_t)b * 4096 + (size_t)zp * 64 + s2;
      yzf[rr][mt] = *(const f16x8*)(outh + col * 4096 + (size_t)(s30 + rr) * 64 + 8 * g);
    }
  f16x8 W1F[4];
#pragma unroll
  for (int nt = 0; nt < 4; ++nt)
    W1F[nt] = *(const f16x8*)(wsh + WS_W1 + (size_t)(nt * 64 + l) * 8);
  float b1v[4];
#pragma unroll
  for (int nt = 0; nt < 4; ++nt) b1v[nt] = b1g[nt * 16 + r];
  {
    f32x4 ya[4][2];
#pragma unroll
    for (int mt = 0; mt < 4; ++mt)
#pragma unroll
      for (int nt = 0; nt < 2; ++nt) ya[mt][nt] = mfma16(Ati[mt], Bp[nt], vzero);
#pragma unroll
    for (int mt = 0; mt < 4; ++mt)
#pragma unroll
      for (int nt = 0; nt < 2; ++nt)
#pragma unroll
        for (int q = 0; q < 4; ++q) {
          int zp = mt * 16 + 4 * g + q, o = nt * 16 + r;
          int rowi = w * 64 + zp;
          YL[rowi * 32 + (((o >> 3) ^ ((rowi >> 2) & 3))) * 8 + (o & 7)] =
              (half_t)ya[mt][nt][q];
        }
  }
  __syncthreads();  // bar4: YL ready; yzf/W1F drained

  // ---- FFN: 2 rounds of 64 rows (col c = rr per round); HL overlays FB+PB ----
  f16x8 W2F[4];
#pragma unroll
  for (int f = 0; f < 4; ++f)
    W2F[f] = *(const f16x8*)(wsh + WS_W2 + (size_t)(f * 64 + l) * 8);
  float b2v[2];
#pragma unroll
  for (int nt = 0; nt < 2; ++nt) b2v[nt] = b2g[nt * 16 + r];

  for (int rr = 0; rr < 2; ++rr) {
    f16x8 AY[2];
#pragma unroll
    for (int mt = 0; mt < 2; ++mt) {
      int rowA = rr * 64 + w * 32 + mt * 16 + r;  // c = rr, zp = w*32+mt*16+r
      f16x8 ay = *(const f16x8*)(YL + rowA * 32 + ((g ^ ((rowA >> 2) & 3))) * 8);
      AY[mt] = ay + yzf[rr][mt];  // fold z-branch (packed f16 adds)
    }
    f32x4 ha[2][4];
#pragma unroll
    for (int mt = 0; mt < 2; ++mt)
#pragma unroll
      for (int nt = 0; nt < 4; ++nt) ha[mt][nt] = mfma16(AY[mt], W1F[nt], vzero);
#pragma unroll
    for (int mt = 0; mt < 2; ++mt)
#pragma unroll
      for (int nt = 0; nt < 4; ++nt)
#pragma unroll
        for (int q = 0; q < 4; ++q) {
          int rloc = w * 32 + mt * 16 + 4 * g + q, n = nt * 16 + r;
          float hv = fmaxf(ha[mt][nt][q] + b1v[nt], 0.f);
          HL[rloc * 64 + (((n >> 3) ^ ((rloc >> 2) & 7))) * 8 + (n & 7)] = (half_t)hv;
        }
    __syncthreads();
    f16x8 AH[2][2];
#pragma unroll
    for (int mt = 0; mt < 2; ++mt)
#pragma unroll
      for (int kt = 0; kt < 2; ++kt) {
        int rowA2 = w * 32 + mt * 16 + r;
        AH[mt][kt] =
            *(const f16x8*)(HL + rowA2 * 64 + (((kt * 4 + g) ^ ((rowA2 >> 2) & 7))) * 8);
      }
    f32x4 oa[2][2];
#pragma unroll
    for (int mt = 0; mt < 2; ++mt)
#pragma unroll
      for (int nt = 0; nt < 2; ++nt) oa[mt][nt] = vzero;
#pragma unroll
    for (int kt = 0; kt < 2; ++kt)
#pragma unroll
      for (int mt = 0; mt < 2; ++mt)
#pragma unroll
        for (int nt = 0; nt < 2; ++nt)
          oa[mt][nt] = mfma16(AH[mt][kt], W2F[kt * 2 + nt], oa[mt][nt]);
#pragma unroll
    for (int mt = 0; mt < 2; ++mt)
#pragma unroll
      for (int nt = 0; nt < 2; ++nt)
#pragma unroll
        for (int q = 0; q < 4; ++q) {
          int zp = w * 32 + mt * 16 + 4 * g + q, o = nt * 16 + r;
          outf[(size_t)b * 8388608 + (size_t)zp * RSTR + (size_t)s2 * 2048 +
               (size_t)(s30 + rr) * 32 + o] = oa[mt][nt][q] + b2v[nt];
        }
    if (rr == 0) __syncthreads();
  }
}

}  // namespace

extern "C" void kernel_launch(void* const* d_in, const int* in_sizes, int n_in,
                              void* d_out, int out_size, void* d_ws, size_t ws_size,
                              hipStream_t stream) {
  const float* x = (const float*)d_in[0];
  const float* wx = (const float*)d_in[1];
  const float* wz = (const float*)d_in[2];
  const float* w1 = (const float*)d_in[3];
  const float* b1 = (const float*)d_in[4];
  const float* w2 = (const float*)d_in[5];
  const float* b2 = (const float*)d_in[6];
  float* out = (float*)d_out;
  half_t* wsh = (half_t*)d_ws;

  hipLaunchKernelGGL(kinit, dim3(68), dim3(256), 0, stream, wx, wz, w1, w2, wsh);
  hipLaunchKernelGGL((kspec<0>), dim3(2048), dim3(256), 0, stream, x, wsh, b1, b2, out);
  hipLaunchKernelGGL(kx2, dim3(8192), dim3(128), 0, stream, x, wsh, b1, b2, out);
}

// Round 13
// 135.644 us; speedup vs baseline: 1.8549x; 1.8549x over previous
//
#include <hip/hip_runtime.h>

namespace {

typedef _Float16 half_t;
typedef half_t f16x2 __attribute__((ext_vector_type(2)));
typedef half_t f16x8 __attribute__((ext_vector_type(8)));
typedef float f32x4 __attribute__((ext_vector_type(4)));

constexpr size_t RSTR = 64 * 64 * 32;  // s1 stride in floats

// ---- ws layout (f16 element offsets), all arrays are [frag][lane][8] packed ----
constexpr int WS_TF = 0;       // forward Tf frags: 4  (mt*2+kt)
constexpr int WS_TI = 2048;    // inverse Ti frags: 4  (mt)
constexpr int WS_WZ = 4096;    // mix W' z-branch: 16 modes x 8 (kt*4+nt)
constexpr int WS_WX = 69632;   // mix W' x-branch
constexpr int WS_W1 = 135168;  // FFN w1 frags: 4 (nt)
constexpr int WS_W2 = 137216;  // FFN w2 frags: 4 (kt*2+nt)
// y_z scratch (WSY=1): f16 offset 524288 (1 MiB bytes), layout [b][s2][s3][s1][o]
//   strides (f16): o:1, s1:32, s3:2048, s2:131072, b:8388608; total 64 MiB.
constexpr size_t WS_YZ = 524288;
constexpr size_t WS_NEED_BYTES = WS_YZ * 2 + 67108864ull;  // 1 MiB + 64 MiB

__device__ __forceinline__ float f4get(const float4& v, int u) {
  return u == 0 ? v.x : (u == 1 ? v.y : (u == 2 ? v.z : v.w));
}

__device__ __forceinline__ f32x4 mfma16(f16x8 a, f16x8 b, f32x4 c) {
  return __builtin_amdgcn_mfma_f32_16x16x32_f16(a, b, c, 0, 0, 0);
}

// Pre-pack all shared MFMA operands into ws, fragment-ordered per lane.
//   lane l: r=l&15, g=l>>4; element e of K-tile kt -> k = kt*32 + 8*g + e
//   A[row=Mtile*16+r][k]; B[k][col=Ntile*16+r]
__global__ __launch_bounds__(256) void kinit(const float* __restrict__ wx,
                                             const float* __restrict__ wz,
                                             const float* __restrict__ w1,
                                             const float* __restrict__ w2,
                                             half_t* __restrict__ wsh) {
  const int id = blockIdx.x * 256 + threadIdx.x;
  const int l = id & 63, r = l & 15, g = l >> 4;
  f16x8 frag;
  if (id < 256) {  // Tf: [mc=2m+p][z], 1/8 norm, -sin folded
    int fid = id >> 6, mt = fid >> 1, kt = fid & 1;
#pragma unroll
    for (int e = 0; e < 8; ++e) {
      int k = kt * 32 + 8 * g + e;  // z
      int mc = mt * 16 + r, m = mc >> 1, p = mc & 1;
      float s, c;
      sincospif((float)(m * k) * (1.0f / 32.0f), &s, &c);
      frag[e] = (half_t)(0.125f * (p ? -s : c));
    }
    *(f16x8*)(wsh + WS_TF + (size_t)id * 8) = frag;
  } else if (id < 512) {  // Ti: [z'][k=2m+p], sc_0=1/8 else 1/4, (cos, -sin)
    int id2 = id - 256, mt = id2 >> 6;
#pragma unroll
    for (int e = 0; e < 8; ++e) {
      int zp = mt * 16 + r;
      int k = 8 * g + e, m = k >> 1, p = k & 1;
      float s, c;
      sincospif((float)(m * zp) * (1.0f / 32.0f), &s, &c);
      float sc = (m == 0) ? 0.125f : 0.25f;
      frag[e] = (half_t)(p ? -sc * s : sc * c);
    }
    *(f16x8*)(wsh + WS_TI + (size_t)id2 * 8) = frag;
  } else if (id < 16896) {  // W' realified: [k=2i+p][n=2o+q] per mode
    int id2 = id - 512;
    const float* wsrc = wz;
    size_t off = WS_WZ;
    if (id2 >= 8192) { id2 -= 8192; wsrc = wx; off = WS_WX; }
    int fid = id2 >> 6, m = fid >> 3, kt = (fid >> 2) & 1, nt = fid & 3;
#pragma unroll
    for (int e = 0; e < 8; ++e) {
      int k = kt * 32 + 8 * g + e, i = k >> 1, p = k & 1;
      int n = nt * 16 + r, o = n >> 1, q = n & 1;
      int base = ((i * 32 + o) * 16 + m) * 2;  // raw [i][o][mode][2]
      float re = wsrc[base], im = wsrc[base + 1];
      frag[e] = (half_t)(q ? (p ? re : im) : (p ? -im : re));
    }
    *(f16x8*)(wsh + off + (size_t)id2 * 8) = frag;
  } else if (id < 17152) {  // w1 [32 k][64 n]
    int id2 = id - 16896, nt = id2 >> 6;
#pragma unroll
    for (int e = 0; e < 8; ++e) {
      int k = 8 * g + e, n = nt * 16 + r;
      frag[e] = (half_t)w1[k * 64 + n];
    }
    *(f16x8*)(wsh + WS_W1 + (size_t)id2 * 8) = frag;
  } else if (id < 17408) {  // w2 [64 k][32 n]
    int id2 = id - 17152, fid = id2 >> 6, kt = fid >> 1, nt = fid & 1;
#pragma unroll
    for (int e = 0; e < 8; ++e) {
      int k = kt * 32 + 8 * g + e, n = nt * 16 + r;
      frag[e] = (half_t)w2[k * 32 + n];
    }
    *(f16x8*)(wsh + WS_W2 + (size_t)id2 * 8) = frag;
  }
}

// ============== z-branch: y_z -> ws T-layout (WSY=1) or d_out slots (WSY=0) ==============
template <int WSY>
__global__ __launch_bounds__(256) void kz(const float* __restrict__ x,
                                          const half_t* __restrict__ wsh,
                                          half_t* __restrict__ yzs,
                                          float* __restrict__ outf) {
  __shared__ __align__(16) char smraw[49152];
  half_t* XB = (half_t*)smraw;            // [256 rows=(c,i)][64 z] swz
  half_t* FB = (half_t*)smraw;            // [16 m][16 c][64 k=2i+p] swz
  half_t* PB = (half_t*)(smraw + 32768);  // [8 c][32 o][32 k=2m+p] swz
  half_t* outh = (half_t*)outf;
  const int t = threadIdx.x, l = t & 63, w = t >> 6, r = l & 15, g = l >> 4;
  const f32x4 vzero = {0.f, 0.f, 0.f, 0.f};

  const int col0 = blockIdx.x * 8;
  size_t xbase = (size_t)col0 * 2048;

  {  // stage x -> XB
    int c = t >> 5, sub = t & 31;
    int i4 = (sub & 7) * 4, zq = sub >> 3;
    const float* xp = x + xbase + (size_t)c * 2048 + i4;
#pragma unroll
    for (int zo = 0; zo < 2; ++zo) {
      int zb = zq * 16 + zo * 8;
      float4 v[8];
#pragma unroll
      for (int zz = 0; zz < 8; ++zz)
        v[zz] = *(const float4*)(xp + (size_t)(zb + zz) * 32);
#pragma unroll
      for (int u = 0; u < 4; ++u) {
        f16x8 rowv;
#pragma unroll
        for (int zz = 0; zz < 8; ++zz) rowv[zz] = (half_t)f4get(v[zz], u);
        int rowi = c * 32 + i4 + u;
        int gr = (zb >> 3) ^ (rowi & 7);
        *(f16x8*)(XB + rowi * 64 + gr * 8) = rowv;
      }
    }
  }
  __syncthreads();

  // forward
  f32x4 fa[2][4];
#pragma unroll
  for (int mt = 0; mt < 2; ++mt)
#pragma unroll
    for (int nt = 0; nt < 4; ++nt) fa[mt][nt] = vzero;
  {
    f16x8 Atf[2][2], Bx[4][2];
#pragma unroll
    for (int mt = 0; mt < 2; ++mt)
#pragma unroll
      for (int kt = 0; kt < 2; ++kt)
        Atf[mt][kt] = *(const f16x8*)(wsh + WS_TF + (size_t)((mt * 2 + kt) * 64 + l) * 8);
#pragma unroll
    for (int nt = 0; nt < 4; ++nt)
#pragma unroll
      for (int kt = 0; kt < 2; ++kt) {
        int rowi = w * 64 + nt * 16 + r;
        int gr = (kt * 4 + g) ^ (rowi & 7);
        Bx[nt][kt] = *(const f16x8*)(XB + rowi * 64 + gr * 8);
      }
#pragma unroll
    for (int kt = 0; kt < 2; ++kt)
#pragma unroll
      for (int nt = 0; nt < 4; ++nt)
#pragma unroll
        for (int mt = 0; mt < 2; ++mt)
          fa[mt][nt] = mfma16(Atf[mt][kt], Bx[nt][kt], fa[mt][nt]);
  }
  __syncthreads();

#pragma unroll
  for (int mt = 0; mt < 2; ++mt)
#pragma unroll
    for (int nt = 0; nt < 4; ++nt)
#pragma unroll
      for (int q = 0; q < 4; ++q) {
        int mc = mt * 16 + 4 * g + q, m = mc >> 1, p = mc & 1;
        int n = w * 64 + nt * 16 + r, c = n >> 5, i = n & 31;
        int k = 2 * i + p;
        FB[(m * 16 + c) * 64 + ((k >> 3) ^ (c & 7)) * 8 + (k & 7)] = (half_t)fa[mt][nt][q];
      }
  __syncthreads();

  // mix
  const half_t* WF = wsh + WS_WZ;
#pragma unroll
  for (int j = 0; j < 4; ++j) {
    int m = w * 4 + j;
    f16x8 Af[2];
#pragma unroll
    for (int kt = 0; kt < 2; ++kt) {
      int gr = (kt * 4 + g) ^ (r & 7);
      Af[kt] = *(const f16x8*)(FB + (m * 16 + r) * 64 + gr * 8);
    }
    f32x4 pa[4];
#pragma unroll
    for (int nt = 0; nt < 4; ++nt) pa[nt] = vzero;
#pragma unroll
    for (int kt = 0; kt < 2; ++kt)
#pragma unroll
      for (int nt = 0; nt < 4; ++nt) {
        f16x8 Bw = *(const f16x8*)(WF + (size_t)((m * 8 + kt * 4 + nt) * 64 + l) * 8);
        pa[nt] = mfma16(Af[kt], Bw, pa[nt]);
      }
#pragma unroll
    for (int nt = 0; nt < 4; ++nt)
#pragma unroll
      for (int q = 0; q < 4; ++q) {
        int c = 4 * g + q;
        if (c < 8) {
          int n = nt * 16 + r, o = n >> 1, q2 = n & 1;
          int k = 2 * m + q2;
          PB[(c * 32 + o) * 32 + ((k >> 3) ^ (o & 3)) * 8 + (k & 7)] = (half_t)pa[nt][q];
        }
      }
  }
  __syncthreads();

  // inverse + store y_z f16
  {
    f16x8 Ati[4];
#pragma unroll
    for (int mt = 0; mt < 4; ++mt)
      Ati[mt] = *(const f16x8*)(wsh + WS_TI + (size_t)(mt * 64 + l) * 8);
#pragma unroll
    for (int cc = 0; cc < 2; ++cc) {
      int c = w * 2 + cc;
      f16x8 Bp[2];
#pragma unroll
      for (int nt = 0; nt < 2; ++nt) {
        int o = nt * 16 + r;
        Bp[nt] = *(const f16x8*)(PB + (c * 32 + o) * 32 + (g ^ (o & 3)) * 8);
      }
      f32x4 ya[4][2];
#pragma unroll
      for (int mt = 0; mt < 4; ++mt)
#pragma unroll
        for (int nt = 0; nt < 2; ++nt) ya[mt][nt] = mfma16(Ati[mt], Bp[nt], vzero);
      const int pcol = col0 + c;
      const int bb = pcol >> 12, s1c = (pcol >> 6) & 63, s2c = pcol & 63;
#pragma unroll
      for (int mt = 0; mt < 4; ++mt)
#pragma unroll
        for (int nt = 0; nt < 2; ++nt)
#pragma unroll
          for (int q = 0; q < 4; ++q) {
            int zp = mt * 16 + 4 * g + q, o = nt * 16 + r;
            if (WSY) {
              yzs[(size_t)bb * 8388608 + (size_t)s2c * 131072 + (size_t)zp * 2048 +
                  s1c * 32 + o] = (half_t)ya[mt][nt][q];
            } else {
              outh[(size_t)pcol * 4096 + zp * 64 + o] = (half_t)ya[mt][nt][q];
            }
          }
    }
  }
}

// ===== x-branch + FFN (round-6 structure; yzf from ws T-layout when WSY=1) =====
template <int WSY>
__global__ __launch_bounds__(256, 4) void kx4(const float* __restrict__ x,
                                              const half_t* __restrict__ wsh,
                                              const half_t* __restrict__ yzs,
                                              const float* __restrict__ b1g,
                                              const float* __restrict__ b2g,
                                              float* __restrict__ outf) {
  __shared__ __align__(16) half_t smh[16384];  // 32 KB
  half_t* XB = smh;            // [128 rows=(c*32+i)][64 z]    16KB  [0,8192)
  half_t* FB = smh + 8192;     // [16 m][4 c][64 k=2i+p]        8KB  [8192,12288)
  half_t* PB = smh + 12288;    // [4 c][32 o][32 k=2m+p]        8KB  [12288,16384)
  half_t* YL = smh;            // [256 rows=(c*64+z')][32 o]   16KB  overlays XB (dead)
  half_t* HL = smh + 8192;     // [128 rows][64 n]             16KB  overlays FB+PB (dead)
  const half_t* outh = (const half_t*)outf;
  const int t = threadIdx.x, l = t & 63, w = t >> 6, r = l & 15, g = l >> 4;
  const f32x4 vzero = {0.f, 0.f, 0.f, 0.f};

  const int d = blockIdx.x;
  const int pp = (d & 7) * 512 + (d >> 3);  // XCD-bijective swizzle (4096 = 8*512)
  const int col0 = pp * 4;
  const int b = col0 >> 12, s2 = (col0 >> 6) & 63, s30 = col0 & 63;
  const size_t xbase = (size_t)b * 8388608 + (size_t)s2 * 2048 + (size_t)s30 * 32;

  {  // ---- stage x -> XB (rows = c*32+i, cols = z = s1) ----
    int sub = t & 31, zq = t >> 5;          // zq in [0,8): granule index
    int c = sub >> 3, i4 = (sub & 7) * 4;
    const float* xp = x + xbase + (size_t)c * 32 + i4 + (size_t)(zq * 8) * RSTR;
    float4 v[8];
#pragma unroll
    for (int zz = 0; zz < 8; ++zz) v[zz] = *(const float4*)(xp + (size_t)zz * RSTR);
#pragma unroll
    for (int uu = 0; uu < 4; ++uu) {
      int u = (uu + sub) & 3;               // lane-rotated to spread banks
      f16x8 rowv;
#pragma unroll
      for (int zz = 0; zz < 8; ++zz) rowv[zz] = (half_t)f4get(v[zz], u);
      int rowi = c * 32 + i4 + u;
      *(f16x8*)(XB + rowi * 64 + (zq ^ (rowi & 7)) * 8) = rowv;
    }
  }
  __syncthreads();  // bar1

  // ---- forward: F[32 mc][128 n=(c,i)] = Tf @ X ----
  f32x4 fa[2][2];
  {
    f16x8 Atf[2][2], Bx[2][2];
#pragma unroll
    for (int mt = 0; mt < 2; ++mt)
#pragma unroll
      for (int kt = 0; kt < 2; ++kt)
        Atf[mt][kt] = *(const f16x8*)(wsh + WS_TF + (size_t)((mt * 2 + kt) * 64 + l) * 8);
#pragma unroll
    for (int nt = 0; nt < 2; ++nt)
#pragma unroll
      for (int kt = 0; kt < 2; ++kt) {
        int rowi = w * 32 + nt * 16 + r;
        Bx[nt][kt] = *(const f16x8*)(XB + rowi * 64 + (((kt * 4 + g) ^ (rowi & 7))) * 8);
      }
#pragma unroll
    for (int mt = 0; mt < 2; ++mt)
#pragma unroll
      for (int nt = 0; nt < 2; ++nt) fa[mt][nt] = vzero;
#pragma unroll
    for (int kt = 0; kt < 2; ++kt)
#pragma unroll
      for (int nt = 0; nt < 2; ++nt)
#pragma unroll
        for (int mt = 0; mt < 2; ++mt)
          fa[mt][nt] = mfma16(Atf[mt][kt], Bx[nt][kt], fa[mt][nt]);
  }
  // FB region is disjoint from XB: no barrier needed before writing.
  // Paired writes: q=(0,1) and (2,3) share m and map to adjacent k.
#pragma unroll
  for (int mt = 0; mt < 2; ++mt)
#pragma unroll
    for (int nt = 0; nt < 2; ++nt)
#pragma unroll
      for (int pr = 0; pr < 2; ++pr) {
        int q = 2 * pr;
        int mc = mt * 16 + 4 * g + q, m = mc >> 1;
        int n = w * 32 + nt * 16 + r, c = n >> 5, i = n & 31;
        int k = 2 * i;
        f16x2 pairv = {(half_t)fa[mt][nt][q], (half_t)fa[mt][nt][q + 1]};
        *(f16x2*)(FB + (m * 4 + c) * 64 + (((k >> 3) ^ ((m + 2 * c) & 7))) * 8 + (k & 7)) =
            pairv;
      }
  __syncthreads();  // bar2: FB ready

  // ---- mix: P_m[c][64 (2o+q)] = F_m @ W'_m; A rows r -> F[m][r&3] (bcast) ----
#pragma unroll
  for (int j = 0; j < 4; ++j) {
    int m = w * 4 + j;
    int rsel = r & 3, keym = (m + 2 * rsel) & 7;
    f16x8 Af[2];
#pragma unroll
    for (int kt = 0; kt < 2; ++kt)
      Af[kt] = *(const f16x8*)(FB + (m * 4 + rsel) * 64 + (((kt * 4 + g) ^ keym)) * 8);
    f32x4 pa[4];
#pragma unroll
    for (int nt = 0; nt < 4; ++nt) pa[nt] = vzero;
#pragma unroll
    for (int kt = 0; kt < 2; ++kt)
#pragma unroll
      for (int nt = 0; nt < 4; ++nt) {
        f16x8 Bw = *(const f16x8*)(wsh + WS_WX + (size_t)((m * 8 + kt * 4 + nt) * 64 + l) * 8);
        pa[nt] = mfma16(Af[kt], Bw, pa[nt]);
      }
    if (g == 0) {  // D rows 0..3 = c
#pragma unroll
      for (int nt = 0; nt < 4; ++nt)
#pragma unroll
        for (int q = 0; q < 4; ++q) {
          int c = q;
          int n = nt * 16 + r, o = n >> 1, q2 = n & 1;
          int k = 2 * m + q2;
          PB[(c * 32 + o) * 32 + (((k >> 3) ^ (o & 3))) * 8 + (k & 7)] = (half_t)pa[nt][q];
        }
    }
  }
  __syncthreads();  // bar3: PB ready

  // ---- inverse (c = w): y_x = Ti @ P_c -> YL (no y_z here) ----
  // Issue order matters (in-order vmcnt): Ati (consumed now) FIRST, then the
  // FFN prefetches (y_z frags + W1) that drain at bar4 under this phase.
  f16x8 Ati[4];
#pragma unroll
  for (int mt = 0; mt < 4; ++mt)
    Ati[mt] = *(const f16x8*)(wsh + WS_TI + (size_t)(mt * 64 + l) * 8);
  f16x8 Bp[2];
#pragma unroll
  for (int nt = 0; nt < 2; ++nt) {
    int o = nt * 16 + r;
    Bp[nt] = *(const f16x8*)(PB + (w * 32 + o) * 32 + ((g ^ (o & 3))) * 8);
  }
  // y_z fragments for FFN rows rowA = rr*128 + w*32 + mt*16 + r:
  //   s3 = s30 + rowA>>6 = s30 + rr*2 + (w>>1); s1 = rowA&63 = (w&1)*32+mt*16+r.
  // WSY=1: T-layout -> lanes (r,g) read 16*64B = 1KB contiguous per instruction.
  f16x8 yzf[2][2];
#pragma unroll
  for (int rr = 0; rr < 2; ++rr)
#pragma unroll
    for (int mt = 0; mt < 2; ++mt) {
      if (WSY) {
        int s3 = s30 + rr * 2 + (w >> 1);
        int s1v = (w & 1) * 32 + mt * 16 + r;
        yzf[rr][mt] = *(const f16x8*)(yzs + (size_t)b * 8388608 + (size_t)s2 * 131072 +
                                      (size_t)s3 * 2048 + s1v * 32 + 8 * g);
      } else {
        int rowA = rr * 128 + w * 32 + mt * 16 + r;
        int zp = rowA & 63, c = rowA >> 6;
        size_t col = (size_t)b * 4096 + (size_t)zp * 64 + s2;
        yzf[rr][mt] = *(const f16x8*)(outh + col * 4096 + (size_t)(s30 + c) * 64 + 8 * g);
      }
    }
  f16x8 W1F[4];
#pragma unroll
  for (int nt = 0; nt < 4; ++nt)
    W1F[nt] = *(const f16x8*)(wsh + WS_W1 + (size_t)(nt * 64 + l) * 8);
  float b1v[4];
#pragma unroll
  for (int nt = 0; nt < 4; ++nt) b1v[nt] = b1g[nt * 16 + r];
  {
    f32x4 ya[4][2];
#pragma unroll
    for (int mt = 0; mt < 4; ++mt)
#pragma unroll
      for (int nt = 0; nt < 2; ++nt) ya[mt][nt] = mfma16(Ati[mt], Bp[nt], vzero);
#pragma unroll
    for (int mt = 0; mt < 4; ++mt)
#pragma unroll
      for (int nt = 0; nt < 2; ++nt)
#pragma unroll
        for (int q = 0; q < 4; ++q) {
          int zp = mt * 16 + 4 * g + q, o = nt * 16 + r;
          int rowi = w * 64 + zp;
          YL[rowi * 32 + (((o >> 3) ^ ((rowi >> 2) & 3))) * 8 + (o & 7)] =
              (half_t)ya[mt][nt][q];
        }
  }
  __syncthreads();  // bar4: YL ready; yzf/W1F drained

  // ---- FFN: 2 rounds of 128 rows; HL overlays FB+PB (dead after inverse) ----
  f16x8 W2F[4];
#pragma unroll
  for (int f = 0; f < 4; ++f)
    W2F[f] = *(const f16x8*)(wsh + WS_W2 + (size_t)(f * 64 + l) * 8);
  float b2v[2];
#pragma unroll
  for (int nt = 0; nt < 2; ++nt) b2v[nt] = b2g[nt * 16 + r];

  for (int rr = 0; rr < 2; ++rr) {
    f16x8 AY[2];
#pragma unroll
    for (int mt = 0; mt < 2; ++mt) {
      int rowA = rr * 128 + w * 32 + mt * 16 + r;
      f16x8 ay = *(const f16x8*)(YL + rowA * 32 + ((g ^ ((rowA >> 2) & 3))) * 8);
      AY[mt] = ay + yzf[rr][mt];  // fold z-branch into FFN input (packed f16 adds)
    }
    f32x4 ha[2][4];
#pragma unroll
    for (int mt = 0; mt < 2; ++mt)
#pragma unroll
      for (int nt = 0; nt < 4; ++nt) ha[mt][nt] = mfma16(AY[mt], W1F[nt], vzero);
#pragma unroll
    for (int mt = 0; mt < 2; ++mt)
#pragma unroll
      for (int nt = 0; nt < 4; ++nt)
#pragma unroll
        for (int q = 0; q < 4; ++q) {
          int rloc = w * 32 + mt * 16 + 4 * g + q, n = nt * 16 + r;
          float hv = fmaxf(ha[mt][nt][q] + b1v[nt], 0.f);
          HL[rloc * 64 + (((n >> 3) ^ ((rloc >> 2) & 7))) * 8 + (n & 7)] = (half_t)hv;
        }
    __syncthreads();
    f16x8 AH[2][2];
#pragma unroll
    for (int mt = 0; mt < 2; ++mt)
#pragma unroll
      for (int kt = 0; kt < 2; ++kt) {
        int rowA2 = w * 32 + mt * 16 + r;
        AH[mt][kt] =
            *(const f16x8*)(HL + rowA2 * 64 + (((kt * 4 + g) ^ ((rowA2 >> 2) & 7))) * 8);
      }
    f32x4 oa[2][2];
#pragma unroll
    for (int mt = 0; mt < 2; ++mt)
#pragma unroll
      for (int nt = 0; nt < 2; ++nt) oa[mt][nt] = vzero;
#pragma unroll
    for (int kt = 0; kt < 2; ++kt)
#pragma unroll
      for (int mt = 0; mt < 2; ++mt)
#pragma unroll
        for (int nt = 0; nt < 2; ++nt)
          oa[mt][nt] = mfma16(AH[mt][kt], W2F[kt * 2 + nt], oa[mt][nt]);
#pragma unroll
    for (int mt = 0; mt < 2; ++mt)
#pragma unroll
      for (int nt = 0; nt < 2; ++nt)
#pragma unroll
        for (int q = 0; q < 4; ++q) {
          int rowg = rr * 128 + w * 32 + mt * 16 + 4 * g + q;
          int c = rowg >> 6, zp = rowg & 63, o = nt * 16 + r;
          outf[(size_t)b * 8388608 + (size_t)zp * RSTR + (size_t)s2 * 2048 +
               (size_t)(s30 + c) * 32 + o] = oa[mt][nt][q] + b2v[nt];
        }
    if (rr == 0) __syncthreads();
  }
}

}  // namespace

extern "C" void kernel_launch(void* const* d_in, const int* in_sizes, int n_in,
                              void* d_out, int out_size, void* d_ws, size_t ws_size,
                              hipStream_t stream) {
  const float* x = (const float*)d_in[0];
  const float* wx = (const float*)d_in[1];
  const float* wz = (const float*)d_in[2];
  const float* w1 = (const float*)d_in[3];
  const float* b1 = (const float*)d_in[4];
  const float* w2 = (const float*)d_in[5];
  const float* b2 = (const float*)d_in[6];
  float* out = (float*)d_out;
  half_t* wsh = (half_t*)d_ws;
  half_t* yzs = wsh + WS_YZ;

  hipLaunchKernelGGL(kinit, dim3(68), dim3(256), 0, stream, wx, wz, w1, w2, wsh);
  if (ws_size >= WS_NEED_BYTES) {
    hipLaunchKernelGGL((kz<1>), dim3(2048), dim3(256), 0, stream, x, wsh, yzs, out);
    hipLaunchKernelGGL((kx4<1>), dim3(4096), dim3(256), 0, stream, x, wsh, yzs, b1, b2, out);
  } else {  // fallback: round-6 behavior, scratch inside d_out
    hipLaunchKernelGGL((kz<0>), dim3(2048), dim3(256), 0, stream, x, wsh, yzs, out);
    hipLaunchKernelGGL((kx4<0>), dim3(4096), dim3(256), 0, stream, x, wsh, yzs, b1, b2, out);
  }
}

// Round 14
// 134.124 us; speedup vs baseline: 1.8760x; 1.0113x over previous
//
#include <hip/hip_runtime.h>

namespace {

typedef _Float16 half_t;
typedef half_t f16x2 __attribute__((ext_vector_type(2)));
typedef half_t f16x8 __attribute__((ext_vector_type(8)));
typedef float f32x4 __attribute__((ext_vector_type(4)));

constexpr size_t RSTR = 64 * 64 * 32;  // s1 stride in floats

// ---- ws layout (f16 element offsets), all arrays are [frag][lane][8] packed ----
constexpr int WS_TF = 0;       // forward Tf frags: 4  (mt*2+kt)
constexpr int WS_TI = 2048;    // inverse Ti frags: 4  (mt)
constexpr int WS_WZ = 4096;    // mix W' z-branch: 16 modes x 8 (kt*4+nt)
constexpr int WS_WX = 69632;   // mix W' x-branch
constexpr int WS_W1 = 135168;  // FFN w1 frags: 4 (nt)
constexpr int WS_W2 = 137216;  // FFN w2 frags: 4 (kt*2+nt)
// y_z scratch (WSY=1): f16 offset 524288 (1 MiB bytes), layout [b][s2][s3][s1][o]
//   strides (f16): o:1, s1:32, s3:2048, s2:131072, b:8388608; total 64 MiB.
constexpr size_t WS_YZ = 524288;
constexpr size_t WS_NEED_BYTES = WS_YZ * 2 + 67108864ull;  // 1 MiB + 64 MiB

__device__ __forceinline__ float f4get(const float4& v, int u) {
  return u == 0 ? v.x : (u == 1 ? v.y : (u == 2 ? v.z : v.w));
}

__device__ __forceinline__ f32x4 mfma16(f16x8 a, f16x8 b, f32x4 c) {
  return __builtin_amdgcn_mfma_f32_16x16x32_f16(a, b, c, 0, 0, 0);
}

// Pre-pack all shared MFMA operands into ws, fragment-ordered per lane.
//   lane l: r=l&15, g=l>>4; element e of K-tile kt -> k = kt*32 + 8*g + e
//   A[row=Mtile*16+r][k]; B[k][col=Ntile*16+r]
__global__ __launch_bounds__(256) void kinit(const float* __restrict__ wx,
                                             const float* __restrict__ wz,
                                             const float* __restrict__ w1,
                                             const float* __restrict__ w2,
                                             half_t* __restrict__ wsh) {
  const int id = blockIdx.x * 256 + threadIdx.x;
  const int l = id & 63, r = l & 15, g = l >> 4;
  f16x8 frag;
  if (id < 256) {  // Tf: [mc=2m+p][z], 1/8 norm, -sin folded
    int fid = id >> 6, mt = fid >> 1, kt = fid & 1;
#pragma unroll
    for (int e = 0; e < 8; ++e) {
      int k = kt * 32 + 8 * g + e;  // z
      int mc = mt * 16 + r, m = mc >> 1, p = mc & 1;
      float s, c;
      sincospif((float)(m * k) * (1.0f / 32.0f), &s, &c);
      frag[e] = (half_t)(0.125f * (p ? -s : c));
    }
    *(f16x8*)(wsh + WS_TF + (size_t)id * 8) = frag;
  } else if (id < 512) {  // Ti: [z'][k=2m+p], sc_0=1/8 else 1/4, (cos, -sin)
    int id2 = id - 256, mt = id2 >> 6;
#pragma unroll
    for (int e = 0; e < 8; ++e) {
      int zp = mt * 16 + r;
      int k = 8 * g + e, m = k >> 1, p = k & 1;
      float s, c;
      sincospif((float)(m * zp) * (1.0f / 32.0f), &s, &c);
      float sc = (m == 0) ? 0.125f : 0.25f;
      frag[e] = (half_t)(p ? -sc * s : sc * c);
    }
    *(f16x8*)(wsh + WS_TI + (size_t)id2 * 8) = frag;
  } else if (id < 16896) {  // W' realified: [k=2i+p][n=2o+q] per mode
    int id2 = id - 512;
    const float* wsrc = wz;
    size_t off = WS_WZ;
    if (id2 >= 8192) { id2 -= 8192; wsrc = wx; off = WS_WX; }
    int fid = id2 >> 6, m = fid >> 3, kt = (fid >> 2) & 1, nt = fid & 3;
#pragma unroll
    for (int e = 0; e < 8; ++e) {
      int k = kt * 32 + 8 * g + e, i = k >> 1, p = k & 1;
      int n = nt * 16 + r, o = n >> 1, q = n & 1;
      int base = ((i * 32 + o) * 16 + m) * 2;  // raw [i][o][mode][2]
      float re = wsrc[base], im = wsrc[base + 1];
      frag[e] = (half_t)(q ? (p ? re : im) : (p ? -im : re));
    }
    *(f16x8*)(wsh + off + (size_t)id2 * 8) = frag;
  } else if (id < 17152) {  // w1 [32 k][64 n]
    int id2 = id - 16896, nt = id2 >> 6;
#pragma unroll
    for (int e = 0; e < 8; ++e) {
      int k = 8 * g + e, n = nt * 16 + r;
      frag[e] = (half_t)w1[k * 64 + n];
    }
    *(f16x8*)(wsh + WS_W1 + (size_t)id2 * 8) = frag;
  } else if (id < 17408) {  // w2 [64 k][32 n]
    int id2 = id - 17152, fid = id2 >> 6, kt = fid >> 1, nt = fid & 1;
#pragma unroll
    for (int e = 0; e < 8; ++e) {
      int k = kt * 32 + 8 * g + e, n = nt * 16 + r;
      frag[e] = (half_t)w2[k * 32 + n];
    }
    *(f16x8*)(wsh + WS_W2 + (size_t)id2 * 8) = frag;
  }
}

// ====== z-branch: y_z -> ws T-layout (WSY=1, s1-paired cols) or d_out slots ======
// WSY=1 col grouping: block d -> b=d>>9, s1 = 2*((d>>4)&31) + (c>>2),
// s2 = 4*(d&15) + (c&3). Each 128B line of yzs {s1 pair}x{o} is then written
// entirely by ONE block (full-line write combining in its XCD's L2).
template <int WSY>
__global__ __launch_bounds__(256) void kz(const float* __restrict__ x,
                                          const half_t* __restrict__ wsh,
                                          half_t* __restrict__ yzs,
                                          float* __restrict__ outf) {
  __shared__ __align__(16) char smraw[49152];
  half_t* XB = (half_t*)smraw;            // [256 rows=(c,i)][64 z] swz
  half_t* FB = (half_t*)smraw;            // [16 m][16 c][64 k=2i+p] swz
  half_t* PB = (half_t*)(smraw + 32768);  // [8 c][32 o][32 k=2m+p] swz
  half_t* outh = (half_t*)outf;
  const int t = threadIdx.x, l = t & 63, w = t >> 6, r = l & 15, g = l >> 4;
  const f32x4 vzero = {0.f, 0.f, 0.f, 0.f};

  const int d = blockIdx.x;
  const int bb = WSY ? (d >> 9) : 0;
  const int s1base = WSY ? 2 * ((d >> 4) & 31) : 0;
  const int s2base = WSY ? 4 * (d & 15) : 0;
  const int col0 = d * 8;  // WSY=0 mapping

  {  // stage x -> XB
    int c = t >> 5, sub = t & 31;
    int i4 = (sub & 7) * 4, zq = sub >> 3;
    size_t colbase;
    if (WSY) {
      int s1c = s1base + (c >> 2), s2c = s2base + (c & 3);
      colbase = (size_t)((bb * 64 + s1c) * 64 + s2c) * 2048;
    } else {
      colbase = (size_t)(col0 + c) * 2048;
    }
    const float* xp = x + colbase + i4;
#pragma unroll
    for (int zo = 0; zo < 2; ++zo) {
      int zb = zq * 16 + zo * 8;
      float4 v[8];
#pragma unroll
      for (int zz = 0; zz < 8; ++zz)
        v[zz] = *(const float4*)(xp + (size_t)(zb + zz) * 32);
#pragma unroll
      for (int u = 0; u < 4; ++u) {
        f16x8 rowv;
#pragma unroll
        for (int zz = 0; zz < 8; ++zz) rowv[zz] = (half_t)f4get(v[zz], u);
        int rowi = c * 32 + i4 + u;
        int gr = (zb >> 3) ^ (rowi & 7);
        *(f16x8*)(XB + rowi * 64 + gr * 8) = rowv;
      }
    }
  }
  __syncthreads();

  // forward
  f32x4 fa[2][4];
#pragma unroll
  for (int mt = 0; mt < 2; ++mt)
#pragma unroll
    for (int nt = 0; nt < 4; ++nt) fa[mt][nt] = vzero;
  {
    f16x8 Atf[2][2], Bx[4][2];
#pragma unroll
    for (int mt = 0; mt < 2; ++mt)
#pragma unroll
      for (int kt = 0; kt < 2; ++kt)
        Atf[mt][kt] = *(const f16x8*)(wsh + WS_TF + (size_t)((mt * 2 + kt) * 64 + l) * 8);
#pragma unroll
    for (int nt = 0; nt < 4; ++nt)
#pragma unroll
      for (int kt = 0; kt < 2; ++kt) {
        int rowi = w * 64 + nt * 16 + r;
        int gr = (kt * 4 + g) ^ (rowi & 7);
        Bx[nt][kt] = *(const f16x8*)(XB + rowi * 64 + gr * 8);
      }
#pragma unroll
    for (int kt = 0; kt < 2; ++kt)
#pragma unroll
      for (int nt = 0; nt < 4; ++nt)
#pragma unroll
        for (int mt = 0; mt < 2; ++mt)
          fa[mt][nt] = mfma16(Atf[mt][kt], Bx[nt][kt], fa[mt][nt]);
  }
  __syncthreads();

#pragma unroll
  for (int mt = 0; mt < 2; ++mt)
#pragma unroll
    for (int nt = 0; nt < 4; ++nt)
#pragma unroll
      for (int q = 0; q < 4; ++q) {
        int mc = mt * 16 + 4 * g + q, m = mc >> 1, p = mc & 1;
        int n = w * 64 + nt * 16 + r, c = n >> 5, i = n & 31;
        int k = 2 * i + p;
        FB[(m * 16 + c) * 64 + ((k >> 3) ^ (c & 7)) * 8 + (k & 7)] = (half_t)fa[mt][nt][q];
      }
  __syncthreads();

  // mix
  const half_t* WF = wsh + WS_WZ;
#pragma unroll
  for (int j = 0; j < 4; ++j) {
    int m = w * 4 + j;
    f16x8 Af[2];
#pragma unroll
    for (int kt = 0; kt < 2; ++kt) {
      int gr = (kt * 4 + g) ^ (r & 7);
      Af[kt] = *(const f16x8*)(FB + (m * 16 + r) * 64 + gr * 8);
    }
    f32x4 pa[4];
#pragma unroll
    for (int nt = 0; nt < 4; ++nt) pa[nt] = vzero;
#pragma unroll
    for (int kt = 0; kt < 2; ++kt)
#pragma unroll
      for (int nt = 0; nt < 4; ++nt) {
        f16x8 Bw = *(const f16x8*)(WF + (size_t)((m * 8 + kt * 4 + nt) * 64 + l) * 8);
        pa[nt] = mfma16(Af[kt], Bw, pa[nt]);
      }
#pragma unroll
    for (int nt = 0; nt < 4; ++nt)
#pragma unroll
      for (int q = 0; q < 4; ++q) {
        int c = 4 * g + q;
        if (c < 8) {
          int n = nt * 16 + r, o = n >> 1, q2 = n & 1;
          int k = 2 * m + q2;
          PB[(c * 32 + o) * 32 + ((k >> 3) ^ (o & 3)) * 8 + (k & 7)] = (half_t)pa[nt][q];
        }
      }
  }
  __syncthreads();

  // inverse + store y_z f16
  {
    f16x8 Ati[4];
#pragma unroll
    for (int mt = 0; mt < 4; ++mt)
      Ati[mt] = *(const f16x8*)(wsh + WS_TI + (size_t)(mt * 64 + l) * 8);
#pragma unroll
    for (int cc = 0; cc < 2; ++cc) {
      int c = w * 2 + cc;
      f16x8 Bp[2];
#pragma unroll
      for (int nt = 0; nt < 2; ++nt) {
        int o = nt * 16 + r;
        Bp[nt] = *(const f16x8*)(PB + (c * 32 + o) * 32 + (g ^ (o & 3)) * 8);
      }
      f32x4 ya[4][2];
#pragma unroll
      for (int mt = 0; mt < 4; ++mt)
#pragma unroll
        for (int nt = 0; nt < 2; ++nt) ya[mt][nt] = mfma16(Ati[mt], Bp[nt], vzero);
      int s1c = s1base + (c >> 2), s2c = s2base + (c & 3);  // WSY=1 mapping
      const int pcol = col0 + c;                            // WSY=0 mapping
#pragma unroll
      for (int mt = 0; mt < 4; ++mt)
#pragma unroll
        for (int nt = 0; nt < 2; ++nt)
#pragma unroll
          for (int q = 0; q < 4; ++q) {
            int zp = mt * 16 + 4 * g + q, o = nt * 16 + r;
            if (WSY) {
              yzs[(size_t)bb * 8388608 + (size_t)s2c * 131072 + (size_t)zp * 2048 +
                  s1c * 32 + o] = (half_t)ya[mt][nt][q];
            } else {
              outh[(size_t)pcol * 4096 + zp * 64 + o] = (half_t)ya[mt][nt][q];
            }
          }
    }
  }
}

// ===== x-branch + FFN (round-12 structure, unchanged: kx=83us verified) =====
template <int WSY>
__global__ __launch_bounds__(256, 4) void kx4(const float* __restrict__ x,
                                              const half_t* __restrict__ wsh,
                                              const half_t* __restrict__ yzs,
                                              const float* __restrict__ b1g,
                                              const float* __restrict__ b2g,
                                              float* __restrict__ outf) {
  __shared__ __align__(16) half_t smh[16384];  // 32 KB
  half_t* XB = smh;            // [128 rows=(c*32+i)][64 z]    16KB  [0,8192)
  half_t* FB = smh + 8192;     // [16 m][4 c][64 k=2i+p]        8KB  [8192,12288)
  half_t* PB = smh + 12288;    // [4 c][32 o][32 k=2m+p]        8KB  [12288,16384)
  half_t* YL = smh;            // [256 rows=(c*64+z')][32 o]   16KB  overlays XB (dead)
  half_t* HL = smh + 8192;     // [128 rows][64 n]             16KB  overlays FB+PB (dead)
  const half_t* outh = (const half_t*)outf;
  const int t = threadIdx.x, l = t & 63, w = t >> 6, r = l & 15, g = l >> 4;
  const f32x4 vzero = {0.f, 0.f, 0.f, 0.f};

  const int d = blockIdx.x;
  const int pp = (d & 7) * 512 + (d >> 3);  // XCD-bijective swizzle (4096 = 8*512)
  const int col0 = pp * 4;
  const int b = col0 >> 12, s2 = (col0 >> 6) & 63, s30 = col0 & 63;
  const size_t xbase = (size_t)b * 8388608 + (size_t)s2 * 2048 + (size_t)s30 * 32;

  {  // ---- stage x -> XB (rows = c*32+i, cols = z = s1) ----
    int sub = t & 31, zq = t >> 5;          // zq in [0,8): granule index
    int c = sub >> 3, i4 = (sub & 7) * 4;
    const float* xp = x + xbase + (size_t)c * 32 + i4 + (size_t)(zq * 8) * RSTR;
    float4 v[8];
#pragma unroll
    for (int zz = 0; zz < 8; ++zz) v[zz] = *(const float4*)(xp + (size_t)zz * RSTR);
#pragma unroll
    for (int uu = 0; uu < 4; ++uu) {
      int u = (uu + sub) & 3;               // lane-rotated to spread banks
      f16x8 rowv;
#pragma unroll
      for (int zz = 0; zz < 8; ++zz) rowv[zz] = (half_t)f4get(v[zz], u);
      int rowi = c * 32 + i4 + u;
      *(f16x8*)(XB + rowi * 64 + (zq ^ (rowi & 7)) * 8) = rowv;
    }
  }
  __syncthreads();  // bar1

  // ---- forward: F[32 mc][128 n=(c,i)] = Tf @ X ----
  f32x4 fa[2][2];
  {
    f16x8 Atf[2][2], Bx[2][2];
#pragma unroll
    for (int mt = 0; mt < 2; ++mt)
#pragma unroll
      for (int kt = 0; kt < 2; ++kt)
        Atf[mt][kt] = *(const f16x8*)(wsh + WS_TF + (size_t)((mt * 2 + kt) * 64 + l) * 8);
#pragma unroll
    for (int nt = 0; nt < 2; ++nt)
#pragma unroll
      for (int kt = 0; kt < 2; ++kt) {
        int rowi = w * 32 + nt * 16 + r;
        Bx[nt][kt] = *(const f16x8*)(XB + rowi * 64 + (((kt * 4 + g) ^ (rowi & 7))) * 8);
      }
#pragma unroll
    for (int mt = 0; mt < 2; ++mt)
#pragma unroll
      for (int nt = 0; nt < 2; ++nt) fa[mt][nt] = vzero;
#pragma unroll
    for (int kt = 0; kt < 2; ++kt)
#pragma unroll
      for (int nt = 0; nt < 2; ++nt)
#pragma unroll
        for (int mt = 0; mt < 2; ++mt)
          fa[mt][nt] = mfma16(Atf[mt][kt], Bx[nt][kt], fa[mt][nt]);
  }
  // FB region is disjoint from XB: no barrier needed before writing.
  // Paired writes: q=(0,1) and (2,3) share m and map to adjacent k.
#pragma unroll
  for (int mt = 0; mt < 2; ++mt)
#pragma unroll
    for (int nt = 0; nt < 2; ++nt)
#pragma unroll
      for (int pr = 0; pr < 2; ++pr) {
        int q = 2 * pr;
        int mc = mt * 16 + 4 * g + q, m = mc >> 1;
        int n = w * 32 + nt * 16 + r, c = n >> 5, i = n & 31;
        int k = 2 * i;
        f16x2 pairv = {(half_t)fa[mt][nt][q], (half_t)fa[mt][nt][q + 1]};
        *(f16x2*)(FB + (m * 4 + c) * 64 + (((k >> 3) ^ ((m + 2 * c) & 7))) * 8 + (k & 7)) =
            pairv;
      }
  __syncthreads();  // bar2: FB ready

  // ---- mix: P_m[c][64 (2o+q)] = F_m @ W'_m; A rows r -> F[m][r&3] (bcast) ----
#pragma unroll
  for (int j = 0; j < 4; ++j) {
    int m = w * 4 + j;
    int rsel = r & 3, keym = (m + 2 * rsel) & 7;
    f16x8 Af[2];
#pragma unroll
    for (int kt = 0; kt < 2; ++kt)
      Af[kt] = *(const f16x8*)(FB + (m * 4 + rsel) * 64 + (((kt * 4 + g) ^ keym)) * 8);
    f32x4 pa[4];
#pragma unroll
    for (int nt = 0; nt < 4; ++nt) pa[nt] = vzero;
#pragma unroll
    for (int kt = 0; kt < 2; ++kt)
#pragma unroll
      for (int nt = 0; nt < 4; ++nt) {
        f16x8 Bw = *(const f16x8*)(wsh + WS_WX + (size_t)((m * 8 + kt * 4 + nt) * 64 + l) * 8);
        pa[nt] = mfma16(Af[kt], Bw, pa[nt]);
      }
    if (g == 0) {  // D rows 0..3 = c
#pragma unroll
      for (int nt = 0; nt < 4; ++nt)
#pragma unroll
        for (int q = 0; q < 4; ++q) {
          int c = q;
          int n = nt * 16 + r, o = n >> 1, q2 = n & 1;
          int k = 2 * m + q2;
          PB[(c * 32 + o) * 32 + (((k >> 3) ^ (o & 3))) * 8 + (k & 7)] = (half_t)pa[nt][q];
        }
    }
  }
  __syncthreads();  // bar3: PB ready

  // ---- inverse (c = w): y_x = Ti @ P_c -> YL (no y_z here) ----
  // Issue order matters (in-order vmcnt): Ati (consumed now) FIRST, then the
  // FFN prefetches (y_z frags + W1) that drain at bar4 under this phase.
  f16x8 Ati[4];
#pragma unroll
  for (int mt = 0; mt < 4; ++mt)
    Ati[mt] = *(const f16x8*)(wsh + WS_TI + (size_t)(mt * 64 + l) * 8);
  f16x8 Bp[2];
#pragma unroll
  for (int nt = 0; nt < 2; ++nt) {
    int o = nt * 16 + r;
    Bp[nt] = *(const f16x8*)(PB + (w * 32 + o) * 32 + ((g ^ (o & 3))) * 8);
  }
  // y_z fragments for FFN rows rowA = rr*128 + w*32 + mt*16 + r:
  //   s3 = s30 + rowA>>6 = s30 + rr*2 + (w>>1); s1 = rowA&63 = (w&1)*32+mt*16+r.
  // WSY=1: T-layout -> lanes (r,g) read 16*64B = 1KB contiguous per instruction.
  f16x8 yzf[2][2];
#pragma unroll
  for (int rr = 0; rr < 2; ++rr)
#pragma unroll
    for (int mt = 0; mt < 2; ++mt) {
      if (WSY) {
        int s3 = s30 + rr * 2 + (w >> 1);
        int s1v = (w & 1) * 32 + mt * 16 + r;
        yzf[rr][mt] = *(const f16x8*)(yzs + (size_t)b * 8388608 + (size_t)s2 * 131072 +
                                      (size_t)s3 * 2048 + s1v * 32 + 8 * g);
      } else {
        int rowA = rr * 128 + w * 32 + mt * 16 + r;
        int zp = rowA & 63, c = rowA >> 6;
        size_t col = (size_t)b * 4096 + (size_t)zp * 64 + s2;
        yzf[rr][mt] = *(const f16x8*)(outh + col * 4096 + (size_t)(s30 + c) * 64 + 8 * g);
      }
    }
  f16x8 W1F[4];
#pragma unroll
  for (int nt = 0; nt < 4; ++nt)
    W1F[nt] = *(const f16x8*)(wsh + WS_W1 + (size_t)(nt * 64 + l) * 8);
  float b1v[4];
#pragma unroll
  for (int nt = 0; nt < 4; ++nt) b1v[nt] = b1g[nt * 16 + r];
  {
    f32x4 ya[4][2];
#pragma unroll
    for (int mt = 0; mt < 4; ++mt)
#pragma unroll
      for (int nt = 0; nt < 2; ++nt) ya[mt][nt] = mfma16(Ati[mt], Bp[nt], vzero);
#pragma unroll
    for (int mt = 0; mt < 4; ++mt)
#pragma unroll
      for (int nt = 0; nt < 2; ++nt)
#pragma unroll
        for (int q = 0; q < 4; ++q) {
          int zp = mt * 16 + 4 * g + q, o = nt * 16 + r;
          int rowi = w * 64 + zp;
          YL[rowi * 32 + (((o >> 3) ^ ((rowi >> 2) & 3))) * 8 + (o & 7)] =
              (half_t)ya[mt][nt][q];
        }
  }
  __syncthreads();  // bar4: YL ready; yzf/W1F drained

  // ---- FFN: 2 rounds of 128 rows; HL overlays FB+PB (dead after inverse) ----
  f16x8 W2F[4];
#pragma unroll
  for (int f = 0; f < 4; ++f)
    W2F[f] = *(const f16x8*)(wsh + WS_W2 + (size_t)(f * 64 + l) * 8);
  float b2v[2];
#pragma unroll
  for (int nt = 0; nt < 2; ++nt) b2v[nt] = b2g[nt * 16 + r];

  for (int rr = 0; rr < 2; ++rr) {
    f16x8 AY[2];
#pragma unroll
    for (int mt = 0; mt < 2; ++mt) {
      int rowA = rr * 128 + w * 32 + mt * 16 + r;
      f16x8 ay = *(const f16x8*)(YL + rowA * 32 + ((g ^ ((rowA >> 2) & 3))) * 8);
      AY[mt] = ay + yzf[rr][mt];  // fold z-branch into FFN input (packed f16 adds)
    }
    f32x4 ha[2][4];
#pragma unroll
    for (int mt = 0; mt < 2; ++mt)
#pragma unroll
      for (int nt = 0; nt < 4; ++nt) ha[mt][nt] = mfma16(AY[mt], W1F[nt], vzero);
#pragma unroll
    for (int mt = 0; mt < 2; ++mt)
#pragma unroll
      for (int nt = 0; nt < 4; ++nt)
#pragma unroll
        for (int q = 0; q < 4; ++q) {
          int rloc = w * 32 + mt * 16 + 4 * g + q, n = nt * 16 + r;
          float hv = fmaxf(ha[mt][nt][q] + b1v[nt], 0.f);
          HL[rloc * 64 + (((n >> 3) ^ ((rloc >> 2) & 7))) * 8 + (n & 7)] = (half_t)hv;
        }
    __syncthreads();
    f16x8 AH[2][2];
#pragma unroll
    for (int mt = 0; mt < 2; ++mt)
#pragma unroll
      for (int kt = 0; kt < 2; ++kt) {
        int rowA2 = w * 32 + mt * 16 + r;
        AH[mt][kt] =
            *(const f16x8*)(HL + rowA2 * 64 + (((kt * 4 + g) ^ ((rowA2 >> 2) & 7))) * 8);
      }
    f32x4 oa[2][2];
#pragma unroll
    for (int mt = 0; mt < 2; ++mt)
#pragma unroll
      for (int nt = 0; nt < 2; ++nt) oa[mt][nt] = vzero;
#pragma unroll
    for (int kt = 0; kt < 2; ++kt)
#pragma unroll
      for (int mt = 0; mt < 2; ++mt)
#pragma unroll
        for (int nt = 0; nt < 2; ++nt)
          oa[mt][nt] = mfma16(AH[mt][kt], W2F[kt * 2 + nt], oa[mt][nt]);
#pragma unroll
    for (int mt = 0; mt < 2; ++mt)
#pragma unroll
      for (int nt = 0; nt < 2; ++nt)
#pragma unroll
        for (int q = 0; q < 4; ++q) {
          int rowg = rr * 128 + w * 32 + mt * 16 + 4 * g + q;
          int c = rowg >> 6, zp = rowg & 63, o = nt * 16 + r;
          outf[(size_t)b * 8388608 + (size_t)zp * RSTR + (size_t)s2 * 2048 +
               (size_t)(s30 + c) * 32 + o] = oa[mt][nt][q] + b2v[nt];
        }
    if (rr == 0) __syncthreads();
  }
}

}  // namespace

extern "C" void kernel_launch(void* const* d_in, const int* in_sizes, int n_in,
                              void* d_out, int out_size, void* d_ws, size_t ws_size,
                              hipStream_t stream) {
  const float* x = (const float*)d_in[0];
  const float* wx = (const float*)d_in[1];
  const float* wz = (const float*)d_in[2];
  const float* w1 = (const float*)d_in[3];
  const float* b1 = (const float*)d_in[4];
  const float* w2 = (const float*)d_in[5];
  const float* b2 = (const float*)d_in[6];
  float* out = (float*)d_out;
  half_t* wsh = (half_t*)d_ws;
  half_t* yzs = wsh + WS_YZ;

  hipLaunchKernelGGL(kinit, dim3(68), dim3(256), 0, stream, wx, wz, w1, w2, wsh);
  if (ws_size >= WS_NEED_BYTES) {
    hipLaunchKernelGGL((kz<1>), dim3(2048), dim3(256), 0, stream, x, wsh, yzs, out);
    hipLaunchKernelGGL((kx4<1>), dim3(4096), dim3(256), 0, stream, x, wsh, yzs, b1, b2, out);
  } else {  // fallback: round-6 behavior, scratch inside d_out
    hipLaunchKernelGGL((kz<0>), dim3(2048), dim3(256), 0, stream, x, wsh, yzs, out);
    hipLaunchKernelGGL((kx4<0>), dim3(4096), dim3(256), 0, stream, x, wsh, yzs, b1, b2, out);
  }
}

// Round 15
// 132.761 us; speedup vs baseline: 1.8952x; 1.0103x over previous
//
#include <hip/hip_runtime.h>

namespace {

typedef _Float16 half_t;
typedef half_t f16x2 __attribute__((ext_vector_type(2)));
typedef half_t f16x8 __attribute__((ext_vector_type(8)));
typedef float f32x4 __attribute__((ext_vector_type(4)));

constexpr size_t RSTR = 64 * 64 * 32;  // s1 stride in floats

// ---- ws layout (f16 element offsets), all arrays are [frag][lane][8] packed ----
constexpr int WS_TF = 0;       // forward Tf frags: 4  (mt*2+kt)
constexpr int WS_TI = 2048;    // inverse Ti frags: 4  (mt)
constexpr int WS_WZ = 4096;    // mix W' z-branch: 16 modes x 8 (kt*4+nt)
constexpr int WS_WX = 69632;   // mix W' x-branch
constexpr int WS_W1 = 135168;  // FFN w1 frags: 4 (nt)
constexpr int WS_W2 = 137216;  // FFN w2 frags: 4 (kt*2+nt)
// y_z scratch (WSY=1): f16 offset 524288 (1 MiB bytes), layout [b][s2][s3][s1][o]
//   strides (f16): o:1, s1:32, s3:2048, s2:131072, b:8388608; total 64 MiB.
constexpr size_t WS_YZ = 524288;
constexpr size_t WS_NEED_BYTES = WS_YZ * 2 + 67108864ull;  // 1 MiB + 64 MiB

__device__ __forceinline__ float f4get(const float4& v, int u) {
  return u == 0 ? v.x : (u == 1 ? v.y : (u == 2 ? v.z : v.w));
}

__device__ __forceinline__ f32x4 mfma16(f16x8 a, f16x8 b, f32x4 c) {
  return __builtin_amdgcn_mfma_f32_16x16x32_f16(a, b, c, 0, 0, 0);
}

// Pre-pack all shared MFMA operands into ws, fragment-ordered per lane.
//   lane l: r=l&15, g=l>>4; element e of K-tile kt -> k = kt*32 + 8*g + e
//   A[row=Mtile*16+r][k]; B[k][col=Ntile*16+r]
__global__ __launch_bounds__(256) void kinit(const float* __restrict__ wx,
                                             const float* __restrict__ wz,
                                             const float* __restrict__ w1,
                                             const float* __restrict__ w2,
                                             half_t* __restrict__ wsh) {
  const int id = blockIdx.x * 256 + threadIdx.x;
  const int l = id & 63, r = l & 15, g = l >> 4;
  f16x8 frag;
  if (id < 256) {  // Tf: [mc=2m+p][z], 1/8 norm, -sin folded
    int fid = id >> 6, mt = fid >> 1, kt = fid & 1;
#pragma unroll
    for (int e = 0; e < 8; ++e) {
      int k = kt * 32 + 8 * g + e;  // z
      int mc = mt * 16 + r, m = mc >> 1, p = mc & 1;
      float s, c;
      sincospif((float)(m * k) * (1.0f / 32.0f), &s, &c);
      frag[e] = (half_t)(0.125f * (p ? -s : c));
    }
    *(f16x8*)(wsh + WS_TF + (size_t)id * 8) = frag;
  } else if (id < 512) {  // Ti: [z'][k=2m+p], sc_0=1/8 else 1/4, (cos, -sin)
    int id2 = id - 256, mt = id2 >> 6;
#pragma unroll
    for (int e = 0; e < 8; ++e) {
      int zp = mt * 16 + r;
      int k = 8 * g + e, m = k >> 1, p = k & 1;
      float s, c;
      sincospif((float)(m * zp) * (1.0f / 32.0f), &s, &c);
      float sc = (m == 0) ? 0.125f : 0.25f;
      frag[e] = (half_t)(p ? -sc * s : sc * c);
    }
    *(f16x8*)(wsh + WS_TI + (size_t)id2 * 8) = frag;
  } else if (id < 16896) {  // W' realified: [k=2i+p][n=2o+q] per mode
    int id2 = id - 512;
    const float* wsrc = wz;
    size_t off = WS_WZ;
    if (id2 >= 8192) { id2 -= 8192; wsrc = wx; off = WS_WX; }
    int fid = id2 >> 6, m = fid >> 3, kt = (fid >> 2) & 1, nt = fid & 3;
#pragma unroll
    for (int e = 0; e < 8; ++e) {
      int k = kt * 32 + 8 * g + e, i = k >> 1, p = k & 1;
      int n = nt * 16 + r, o = n >> 1, q = n & 1;
      int base = ((i * 32 + o) * 16 + m) * 2;  // raw [i][o][mode][2]
      float re = wsrc[base], im = wsrc[base + 1];
      frag[e] = (half_t)(q ? (p ? re : im) : (p ? -im : re));
    }
    *(f16x8*)(wsh + off + (size_t)id2 * 8) = frag;
  } else if (id < 17152) {  // w1 [32 k][64 n]
    int id2 = id - 16896, nt = id2 >> 6;
#pragma unroll
    for (int e = 0; e < 8; ++e) {
      int k = 8 * g + e, n = nt * 16 + r;
      frag[e] = (half_t)w1[k * 64 + n];
    }
    *(f16x8*)(wsh + WS_W1 + (size_t)id2 * 8) = frag;
  } else if (id < 17408) {  // w2 [64 k][32 n]
    int id2 = id - 17152, fid = id2 >> 6, kt = fid >> 1, nt = fid & 1;
#pragma unroll
    for (int e = 0; e < 8; ++e) {
      int k = kt * 32 + 8 * g + e, n = nt * 16 + r;
      frag[e] = (half_t)w2[k * 32 + n];
    }
    *(f16x8*)(wsh + WS_W2 + (size_t)id2 * 8) = frag;
  }
}

// ====== z-branch: y_z -> ws T-layout (WSY=1, LDS-staged full-line writes) ======
// WSY=1 col grouping: block d -> b=d>>9, s1 = 2*((d>>4)&31) + (c>>2),
// s2 = 4*(d&15) + (c&3). Block's yzs footprint = 32KB of full 128B lines.
// Inverse stages into an LDS image; copy-out streams 1KB (8 full lines) per
// wave-instruction -- no partial-line L2 write-combining stalls.
template <int WSY>
__global__ __launch_bounds__(256) void kz(const float* __restrict__ x,
                                          const half_t* __restrict__ wsh,
                                          half_t* __restrict__ yzs,
                                          float* __restrict__ outf) {
  __shared__ __align__(16) char smraw[49152];
  half_t* XB = (half_t*)smraw;            // [256 rows=(c,i)][64 z] swz
  half_t* FB = (half_t*)smraw;            // [16 m][16 c][64 k=2i+p] swz
  half_t* PB = (half_t*)(smraw + 32768);  // [8 c][32 o][32 k=2m+p] swz
  half_t* LY = (half_t*)smraw;            // WSY=1: [s2i 4][zp 64][s1i 2][o 32] 32KB
  half_t* outh = (half_t*)outf;
  const int t = threadIdx.x, l = t & 63, w = t >> 6, r = l & 15, g = l >> 4;
  const f32x4 vzero = {0.f, 0.f, 0.f, 0.f};

  const int d = blockIdx.x;
  const int bb = WSY ? (d >> 9) : 0;
  const int s1base = WSY ? 2 * ((d >> 4) & 31) : 0;
  const int s2base = WSY ? 4 * (d & 15) : 0;
  const int col0 = d * 8;  // WSY=0 mapping

  {  // stage x -> XB
    int c = t >> 5, sub = t & 31;
    int i4 = (sub & 7) * 4, zq = sub >> 3;
    size_t colbase;
    if (WSY) {
      int s1c = s1base + (c >> 2), s2c = s2base + (c & 3);
      colbase = (size_t)((bb * 64 + s1c) * 64 + s2c) * 2048;
    } else {
      colbase = (size_t)(col0 + c) * 2048;
    }
    const float* xp = x + colbase + i4;
#pragma unroll
    for (int zo = 0; zo < 2; ++zo) {
      int zb = zq * 16 + zo * 8;
      float4 v[8];
#pragma unroll
      for (int zz = 0; zz < 8; ++zz)
        v[zz] = *(const float4*)(xp + (size_t)(zb + zz) * 32);
#pragma unroll
      for (int u = 0; u < 4; ++u) {
        f16x8 rowv;
#pragma unroll
        for (int zz = 0; zz < 8; ++zz) rowv[zz] = (half_t)f4get(v[zz], u);
        int rowi = c * 32 + i4 + u;
        int gr = (zb >> 3) ^ (rowi & 7);
        *(f16x8*)(XB + rowi * 64 + gr * 8) = rowv;
      }
    }
  }
  __syncthreads();

  // forward
  f32x4 fa[2][4];
#pragma unroll
  for (int mt = 0; mt < 2; ++mt)
#pragma unroll
    for (int nt = 0; nt < 4; ++nt) fa[mt][nt] = vzero;
  {
    f16x8 Atf[2][2], Bx[4][2];
#pragma unroll
    for (int mt = 0; mt < 2; ++mt)
#pragma unroll
      for (int kt = 0; kt < 2; ++kt)
        Atf[mt][kt] = *(const f16x8*)(wsh + WS_TF + (size_t)((mt * 2 + kt) * 64 + l) * 8);
#pragma unroll
    for (int nt = 0; nt < 4; ++nt)
#pragma unroll
      for (int kt = 0; kt < 2; ++kt) {
        int rowi = w * 64 + nt * 16 + r;
        int gr = (kt * 4 + g) ^ (rowi & 7);
        Bx[nt][kt] = *(const f16x8*)(XB + rowi * 64 + gr * 8);
      }
#pragma unroll
    for (int kt = 0; kt < 2; ++kt)
#pragma unroll
      for (int nt = 0; nt < 4; ++nt)
#pragma unroll
        for (int mt = 0; mt < 2; ++mt)
          fa[mt][nt] = mfma16(Atf[mt][kt], Bx[nt][kt], fa[mt][nt]);
  }
  __syncthreads();

#pragma unroll
  for (int mt = 0; mt < 2; ++mt)
#pragma unroll
    for (int nt = 0; nt < 4; ++nt)
#pragma unroll
      for (int q = 0; q < 4; ++q) {
        int mc = mt * 16 + 4 * g + q, m = mc >> 1, p = mc & 1;
        int n = w * 64 + nt * 16 + r, c = n >> 5, i = n & 31;
        int k = 2 * i + p;
        FB[(m * 16 + c) * 64 + ((k >> 3) ^ (c & 7)) * 8 + (k & 7)] = (half_t)fa[mt][nt][q];
      }
  __syncthreads();

  // mix
  const half_t* WF = wsh + WS_WZ;
#pragma unroll
  for (int j = 0; j < 4; ++j) {
    int m = w * 4 + j;
    f16x8 Af[2];
#pragma unroll
    for (int kt = 0; kt < 2; ++kt) {
      int gr = (kt * 4 + g) ^ (r & 7);
      Af[kt] = *(const f16x8*)(FB + (m * 16 + r) * 64 + gr * 8);
    }
    f32x4 pa[4];
#pragma unroll
    for (int nt = 0; nt < 4; ++nt) pa[nt] = vzero;
#pragma unroll
    for (int kt = 0; kt < 2; ++kt)
#pragma unroll
      for (int nt = 0; nt < 4; ++nt) {
        f16x8 Bw = *(const f16x8*)(WF + (size_t)((m * 8 + kt * 4 + nt) * 64 + l) * 8);
        pa[nt] = mfma16(Af[kt], Bw, pa[nt]);
      }
#pragma unroll
    for (int nt = 0; nt < 4; ++nt)
#pragma unroll
      for (int q = 0; q < 4; ++q) {
        int c = 4 * g + q;
        if (c < 8) {
          int n = nt * 16 + r, o = n >> 1, q2 = n & 1;
          int k = 2 * m + q2;
          PB[(c * 32 + o) * 32 + ((k >> 3) ^ (o & 3)) * 8 + (k & 7)] = (half_t)pa[nt][q];
        }
      }
  }
  __syncthreads();

  // inverse: WSY=1 -> stage into LY (over FB, dead); WSY=0 -> direct d_out slots
  {
    f16x8 Ati[4];
#pragma unroll
    for (int mt = 0; mt < 4; ++mt)
      Ati[mt] = *(const f16x8*)(wsh + WS_TI + (size_t)(mt * 64 + l) * 8);
#pragma unroll
    for (int cc = 0; cc < 2; ++cc) {
      int c = w * 2 + cc;
      f16x8 Bp[2];
#pragma unroll
      for (int nt = 0; nt < 2; ++nt) {
        int o = nt * 16 + r;
        Bp[nt] = *(const f16x8*)(PB + (c * 32 + o) * 32 + (g ^ (o & 3)) * 8);
      }
      f32x4 ya[4][2];
#pragma unroll
      for (int mt = 0; mt < 4; ++mt)
#pragma unroll
        for (int nt = 0; nt < 2; ++nt) ya[mt][nt] = mfma16(Ati[mt], Bp[nt], vzero);
      const int s1i = c >> 2, s2i = c & 3;  // WSY=1 mapping
      const int pcol = col0 + c;            // WSY=0 mapping
#pragma unroll
      for (int mt = 0; mt < 4; ++mt)
#pragma unroll
        for (int nt = 0; nt < 2; ++nt)
#pragma unroll
          for (int q = 0; q < 4; ++q) {
            int zp = mt * 16 + 4 * g + q, o = nt * 16 + r;
            if (WSY) {
              LY[s2i * 4096 + zp * 64 + s1i * 32 + o] = (half_t)ya[mt][nt][q];
            } else {
              outh[(size_t)pcol * 4096 + zp * 64 + o] = (half_t)ya[mt][nt][q];
            }
          }
    }
  }
  if (WSY) {
    __syncthreads();  // LY complete
    // copy-out: granule gi (16B) -> global; lanes t consecutive => 64 consecutive
    // granules = 1KB per instruction = 8 FULL 128B lines (at 4KB stride).
    const size_t gbase =
        (size_t)bb * 8388608 + (size_t)s2base * 131072 + (size_t)s1base * 32;
    const half_t* LYc = (const half_t*)smraw;
#pragma unroll
    for (int k = 0; k < 8; ++k) {
      int gi = t + k * 256;
      int o4 = gi & 3, s1i = (gi >> 2) & 1, zp = (gi >> 3) & 63, s2i = gi >> 9;
      *(f16x8*)(yzs + gbase + (size_t)s2i * 131072 + (size_t)zp * 2048 + s1i * 32 +
                o4 * 8) = *(const f16x8*)(LYc + (size_t)gi * 8);
    }
  }
}

// ===== x-branch + FFN (round-12 structure, unchanged: kx=83us verified) =====
template <int WSY>
__global__ __launch_bounds__(256, 4) void kx4(const float* __restrict__ x,
                                              const half_t* __restrict__ wsh,
                                              const half_t* __restrict__ yzs,
                                              const float* __restrict__ b1g,
                                              const float* __restrict__ b2g,
                                              float* __restrict__ outf) {
  __shared__ __align__(16) half_t smh[16384];  // 32 KB
  half_t* XB = smh;            // [128 rows=(c*32+i)][64 z]    16KB  [0,8192)
  half_t* FB = smh + 8192;     // [16 m][4 c][64 k=2i+p]        8KB  [8192,12288)
  half_t* PB = smh + 12288;    // [4 c][32 o][32 k=2m+p]        8KB  [12288,16384)
  half_t* YL = smh;            // [256 rows=(c*64+z')][32 o]   16KB  overlays XB (dead)
  half_t* HL = smh + 8192;     // [128 rows][64 n]             16KB  overlays FB+PB (dead)
  const half_t* outh = (const half_t*)outf;
  const int t = threadIdx.x, l = t & 63, w = t >> 6, r = l & 15, g = l >> 4;
  const f32x4 vzero = {0.f, 0.f, 0.f, 0.f};

  const int d = blockIdx.x;
  const int pp = (d & 7) * 512 + (d >> 3);  // XCD-bijective swizzle (4096 = 8*512)
  const int col0 = pp * 4;
  const int b = col0 >> 12, s2 = (col0 >> 6) & 63, s30 = col0 & 63;
  const size_t xbase = (size_t)b * 8388608 + (size_t)s2 * 2048 + (size_t)s30 * 32;

  {  // ---- stage x -> XB (rows = c*32+i, cols = z = s1) ----
    int sub = t & 31, zq = t >> 5;          // zq in [0,8): granule index
    int c = sub >> 3, i4 = (sub & 7) * 4;
    const float* xp = x + xbase + (size_t)c * 32 + i4 + (size_t)(zq * 8) * RSTR;
    float4 v[8];
#pragma unroll
    for (int zz = 0; zz < 8; ++zz) v[zz] = *(const float4*)(xp + (size_t)zz * RSTR);
#pragma unroll
    for (int uu = 0; uu < 4; ++uu) {
      int u = (uu + sub) & 3;               // lane-rotated to spread banks
      f16x8 rowv;
#pragma unroll
      for (int zz = 0; zz < 8; ++zz) rowv[zz] = (half_t)f4get(v[zz], u);
      int rowi = c * 32 + i4 + u;
      *(f16x8*)(XB + rowi * 64 + (zq ^ (rowi & 7)) * 8) = rowv;
    }
  }
  __syncthreads();  // bar1

  // ---- forward: F[32 mc][128 n=(c,i)] = Tf @ X ----
  f32x4 fa[2][2];
  {
    f16x8 Atf[2][2], Bx[2][2];
#pragma unroll
    for (int mt = 0; mt < 2; ++mt)
#pragma unroll
      for (int kt = 0; kt < 2; ++kt)
        Atf[mt][kt] = *(const f16x8*)(wsh + WS_TF + (size_t)((mt * 2 + kt) * 64 + l) * 8);
#pragma unroll
    for (int nt = 0; nt < 2; ++nt)
#pragma unroll
      for (int kt = 0; kt < 2; ++kt) {
        int rowi = w * 32 + nt * 16 + r;
        Bx[nt][kt] = *(const f16x8*)(XB + rowi * 64 + (((kt * 4 + g) ^ (rowi & 7))) * 8);
      }
#pragma unroll
    for (int mt = 0; mt < 2; ++mt)
#pragma unroll
      for (int nt = 0; nt < 2; ++nt) fa[mt][nt] = vzero;
#pragma unroll
    for (int kt = 0; kt < 2; ++kt)
#pragma unroll
      for (int nt = 0; nt < 2; ++nt)
#pragma unroll
        for (int mt = 0; mt < 2; ++mt)
          fa[mt][nt] = mfma16(Atf[mt][kt], Bx[nt][kt], fa[mt][nt]);
  }
  // FB region is disjoint from XB: no barrier needed before writing.
  // Paired writes: q=(0,1) and (2,3) share m and map to adjacent k.
#pragma unroll
  for (int mt = 0; mt < 2; ++mt)
#pragma unroll
    for (int nt = 0; nt < 2; ++nt)
#pragma unroll
      for (int pr = 0; pr < 2; ++pr) {
        int q = 2 * pr;
        int mc = mt * 16 + 4 * g + q, m = mc >> 1;
        int n = w * 32 + nt * 16 + r, c = n >> 5, i = n & 31;
        int k = 2 * i;
        f16x2 pairv = {(half_t)fa[mt][nt][q], (half_t)fa[mt][nt][q + 1]};
        *(f16x2*)(FB + (m * 4 + c) * 64 + (((k >> 3) ^ ((m + 2 * c) & 7))) * 8 + (k & 7)) =
            pairv;
      }
  __syncthreads();  // bar2: FB ready

  // ---- mix: P_m[c][64 (2o+q)] = F_m @ W'_m; A rows r -> F[m][r&3] (bcast) ----
#pragma unroll
  for (int j = 0; j < 4; ++j) {
    int m = w * 4 + j;
    int rsel = r & 3, keym = (m + 2 * rsel) & 7;
    f16x8 Af[2];
#pragma unroll
    for (int kt = 0; kt < 2; ++kt)
      Af[kt] = *(const f16x8*)(FB + (m * 4 + rsel) * 64 + (((kt * 4 + g) ^ keym)) * 8);
    f32x4 pa[4];
#pragma unroll
    for (int nt = 0; nt < 4; ++nt) pa[nt] = vzero;
#pragma unroll
    for (int kt = 0; kt < 2; ++kt)
#pragma unroll
      for (int nt = 0; nt < 4; ++nt) {
        f16x8 Bw = *(const f16x8*)(wsh + WS_WX + (size_t)((m * 8 + kt * 4 + nt) * 64 + l) * 8);
        pa[nt] = mfma16(Af[kt], Bw, pa[nt]);
      }
    if (g == 0) {  // D rows 0..3 = c
#pragma unroll
      for (int nt = 0; nt < 4; ++nt)
#pragma unroll
        for (int q = 0; q < 4; ++q) {
          int c = q;
          int n = nt * 16 + r, o = n >> 1, q2 = n & 1;
          int k = 2 * m + q2;
          PB[(c * 32 + o) * 32 + (((k >> 3) ^ (o & 3))) * 8 + (k & 7)] = (half_t)pa[nt][q];
        }
    }
  }
  __syncthreads();  // bar3: PB ready

  // ---- inverse (c = w): y_x = Ti @ P_c -> YL (no y_z here) ----
  // Issue order matters (in-order vmcnt): Ati (consumed now) FIRST, then the
  // FFN prefetches (y_z frags + W1) that drain at bar4 under this phase.
  f16x8 Ati[4];
#pragma unroll
  for (int mt = 0; mt < 4; ++mt)
    Ati[mt] = *(const f16x8*)(wsh + WS_TI + (size_t)(mt * 64 + l) * 8);
  f16x8 Bp[2];
#pragma unroll
  for (int nt = 0; nt < 2; ++nt) {
    int o = nt * 16 + r;
    Bp[nt] = *(const f16x8*)(PB + (w * 32 + o) * 32 + ((g ^ (o & 3))) * 8);
  }
  // y_z fragments for FFN rows rowA = rr*128 + w*32 + mt*16 + r:
  //   s3 = s30 + rowA>>6 = s30 + rr*2 + (w>>1); s1 = rowA&63 = (w&1)*32+mt*16+r.
  // WSY=1: T-layout -> lanes (r,g) read 16*64B = 1KB contiguous per instruction.
  f16x8 yzf[2][2];
#pragma unroll
  for (int rr = 0; rr < 2; ++rr)
#pragma unroll
    for (int mt = 0; mt < 2; ++mt) {
      if (WSY) {
        int s3 = s30 + rr * 2 + (w >> 1);
        int s1v = (w & 1) * 32 + mt * 16 + r;
        yzf[rr][mt] = *(const f16x8*)(yzs + (size_t)b * 8388608 + (size_t)s2 * 131072 +
                                      (size_t)s3 * 2048 + s1v * 32 + 8 * g);
      } else {
        int rowA = rr * 128 + w * 32 + mt * 16 + r;
        int zp = rowA & 63, c = rowA >> 6;
        size_t col = (size_t)b * 4096 + (size_t)zp * 64 + s2;
        yzf[rr][mt] = *(const f16x8*)(outh + col * 4096 + (size_t)(s30 + c) * 64 + 8 * g);
      }
    }
  f16x8 W1F[4];
#pragma unroll
  for (int nt = 0; nt < 4; ++nt)
    W1F[nt] = *(const f16x8*)(wsh + WS_W1 + (size_t)(nt * 64 + l) * 8);
  float b1v[4];
#pragma unroll
  for (int nt = 0; nt < 4; ++nt) b1v[nt] = b1g[nt * 16 + r];
  {
    f32x4 ya[4][2];
#pragma unroll
    for (int mt = 0; mt < 4; ++mt)
#pragma unroll
      for (int nt = 0; nt < 2; ++nt) ya[mt][nt] = mfma16(Ati[mt], Bp[nt], vzero);
#pragma unroll
    for (int mt = 0; mt < 4; ++mt)
#pragma unroll
      for (int nt = 0; nt < 2; ++nt)
#pragma unroll
        for (int q = 0; q < 4; ++q) {
          int zp = mt * 16 + 4 * g + q, o = nt * 16 + r;
          int rowi = w * 64 + zp;
          YL[rowi * 32 + (((o >> 3) ^ ((rowi >> 2) & 3))) * 8 + (o & 7)] =
              (half_t)ya[mt][nt][q];
        }
  }
  __syncthreads();  // bar4: YL ready; yzf/W1F drained

  // ---- FFN: 2 rounds of 128 rows; HL overlays FB+PB (dead after inverse) ----
  f16x8 W2F[4];
#pragma unroll
  for (int f = 0; f < 4; ++f)
    W2F[f] = *(const f16x8*)(wsh + WS_W2 + (size_t)(f * 64 + l) * 8);
  float b2v[2];
#pragma unroll
  for (int nt = 0; nt < 2; ++nt) b2v[nt] = b2g[nt * 16 + r];

  for (int rr = 0; rr < 2; ++rr) {
    f16x8 AY[2];
#pragma unroll
    for (int mt = 0; mt < 2; ++mt) {
      int rowA = rr * 128 + w * 32 + mt * 16 + r;
      f16x8 ay = *(const f16x8*)(YL + rowA * 32 + ((g ^ ((rowA >> 2) & 3))) * 8);
      AY[mt] = ay + yzf[rr][mt];  // fold z-branch into FFN input (packed f16 adds)
    }
    f32x4 ha[2][4];
#pragma unroll
    for (int mt = 0; mt < 2; ++mt)
#pragma unroll
      for (int nt = 0; nt < 4; ++nt) ha[mt][nt] = mfma16(AY[mt], W1F[nt], vzero);
#pragma unroll
    for (int mt = 0; mt < 2; ++mt)
#pragma unroll
      for (int nt = 0; nt < 4; ++nt)
#pragma unroll
        for (int q = 0; q < 4; ++q) {
          int rloc = w * 32 + mt * 16 + 4 * g + q, n = nt * 16 + r;
          float hv = fmaxf(ha[mt][nt][q] + b1v[nt], 0.f);
          HL[rloc * 64 + (((n >> 3) ^ ((rloc >> 2) & 7))) * 8 + (n & 7)] = (half_t)hv;
        }
    __syncthreads();
    f16x8 AH[2][2];
#pragma unroll
    for (int mt = 0; mt < 2; ++mt)
#pragma unroll
      for (int kt = 0; kt < 2; ++kt) {
        int rowA2 = w * 32 + mt * 16 + r;
        AH[mt][kt] =
            *(const f16x8*)(HL + rowA2 * 64 + (((kt * 4 + g) ^ ((rowA2 >> 2) & 7))) * 8);
      }
    f32x4 oa[2][2];
#pragma unroll
    for (int mt = 0; mt < 2; ++mt)
#pragma unroll
      for (int nt = 0; nt < 2; ++nt) oa[mt][nt] = vzero;
#pragma unroll
    for (int kt = 0; kt < 2; ++kt)
#pragma unroll
      for (int mt = 0; mt < 2; ++mt)
#pragma unroll
        for (int nt = 0; nt < 2; ++nt)
          oa[mt][nt] = mfma16(AH[mt][kt], W2F[kt * 2 + nt], oa[mt][nt]);
#pragma unroll
    for (int mt = 0; mt < 2; ++mt)
#pragma unroll
      for (int nt = 0; nt < 2; ++nt)
#pragma unroll
        for (int q = 0; q < 4; ++q) {
          int rowg = rr * 128 + w * 32 + mt * 16 + 4 * g + q;
          int c = rowg >> 6, zp = rowg & 63, o = nt * 16 + r;
          outf[(size_t)b * 8388608 + (size_t)zp * RSTR + (size_t)s2 * 2048 +
               (size_t)(s30 + c) * 32 + o] = oa[mt][nt][q] + b2v[nt];
        }
    if (rr == 0) __syncthreads();
  }
}

}  // namespace

extern "C" void kernel_launch(void* const* d_in, const int* in_sizes, int n_in,
                              void* d_out, int out_size, void* d_ws, size_t ws_size,
                              hipStream_t stream) {
  const float* x = (const float*)d_in[0];
  const float* wx = (const float*)d_in[1];
  const float* wz = (const float*)d_in[2];
  const float* w1 = (const float*)d_in[3];
  const float* b1 = (const float*)d_in[4];
  const float* w2 = (const float*)d_in[5];
  const float* b2 = (const float*)d_in[6];
  float* out = (float*)d_out;
  half_t* wsh = (half_t*)d_ws;
  half_t* yzs = wsh + WS_YZ;

  hipLaunchKernelGGL(kinit, dim3(68), dim3(256), 0, stream, wx, wz, w1, w2, wsh);
  if (ws_size >= WS_NEED_BYTES) {
    hipLaunchKernelGGL((kz<1>), dim3(2048), dim3(256), 0, stream, x, wsh, yzs, out);
    hipLaunchKernelGGL((kx4<1>), dim3(4096), dim3(256), 0, stream, x, wsh, yzs, b1, b2, out);
  } else {  // fallback: round-6 behavior, scratch inside d_out
    hipLaunchKernelGGL((kz<0>), dim3(2048), dim3(256), 0, stream, x, wsh, yzs, out);
    hipLaunchKernelGGL((kx4<0>), dim3(4096), dim3(256), 0, stream, x, wsh, yzs, b1, b2, out);
  }
}

// Round 16
// 122.447 us; speedup vs baseline: 2.0549x; 1.0842x over previous
//
#include <hip/hip_runtime.h>

namespace {

typedef _Float16 half_t;
typedef half_t f16x2 __attribute__((ext_vector_type(2)));
typedef half_t f16x8 __attribute__((ext_vector_type(8)));
typedef float f32x4 __attribute__((ext_vector_type(4)));

constexpr size_t RSTR = 64 * 64 * 32;  // s1 stride in floats

// ---- ws layout (f16 element offsets): tables only ----
constexpr int WS_TF = 0;       // forward Tf frags: 4  (mt*2+kt)
constexpr int WS_TI = 2048;    // inverse Ti frags: 4  (mt)
constexpr int WS_WZ = 4096;    // mix W' z-branch: 16 modes x 8 (kt*4+nt)
constexpr int WS_WX = 69632;   // mix W' x-branch
constexpr int WS_W1 = 135168;  // FFN w1 frags: 4 (nt)
constexpr int WS_W2 = 137216;  // FFN w2 frags: 4 (kt*2+nt)

// y_z scratch lives INSIDE d_out (f16 view), at addresses private to the kx
// block that overwrites them (L3-aliased: never flushes to HBM).
//   value (b,s1,s2,s3,o) -> f16 addr:
//     b*16777216 + ((s3&1)*32 + (s1>>1))*262144 + s2*4096
//     + ((s3>>2)*4 + ((s3>>1)&1))*64 + (s1&1)*32 + o
// Single writer: kz block owning (s1 pair, s2). Single reader: kx block
// (b,s2,s30=s3&~3); reads complete before its out-stores (bar4).

__device__ __forceinline__ float f4get(const float4& v, int u) {
  return u == 0 ? v.x : (u == 1 ? v.y : (u == 2 ? v.z : v.w));
}

__device__ __forceinline__ f32x4 mfma16(f16x8 a, f16x8 b, f32x4 c) {
  return __builtin_amdgcn_mfma_f32_16x16x32_f16(a, b, c, 0, 0, 0);
}

// Pre-pack all shared MFMA operands into ws, fragment-ordered per lane.
//   lane l: r=l&15, g=l>>4; element e of K-tile kt -> k = kt*32 + 8*g + e
//   A[row=Mtile*16+r][k]; B[k][col=Ntile*16+r]
__global__ __launch_bounds__(256) void kinit(const float* __restrict__ wx,
                                             const float* __restrict__ wz,
                                             const float* __restrict__ w1,
                                             const float* __restrict__ w2,
                                             half_t* __restrict__ wsh) {
  const int id = blockIdx.x * 256 + threadIdx.x;
  const int l = id & 63, r = l & 15, g = l >> 4;
  f16x8 frag;
  if (id < 256) {  // Tf: [mc=2m+p][z], 1/8 norm, -sin folded
    int fid = id >> 6, mt = fid >> 1, kt = fid & 1;
#pragma unroll
    for (int e = 0; e < 8; ++e) {
      int k = kt * 32 + 8 * g + e;  // z
      int mc = mt * 16 + r, m = mc >> 1, p = mc & 1;
      float s, c;
      sincospif((float)(m * k) * (1.0f / 32.0f), &s, &c);
      frag[e] = (half_t)(0.125f * (p ? -s : c));
    }
    *(f16x8*)(wsh + WS_TF + (size_t)id * 8) = frag;
  } else if (id < 512) {  // Ti: [z'][k=2m+p], sc_0=1/8 else 1/4, (cos, -sin)
    int id2 = id - 256, mt = id2 >> 6;
#pragma unroll
    for (int e = 0; e < 8; ++e) {
      int zp = mt * 16 + r;
      int k = 8 * g + e, m = k >> 1, p = k & 1;
      float s, c;
      sincospif((float)(m * zp) * (1.0f / 32.0f), &s, &c);
      float sc = (m == 0) ? 0.125f : 0.25f;
      frag[e] = (half_t)(p ? -sc * s : sc * c);
    }
    *(f16x8*)(wsh + WS_TI + (size_t)id2 * 8) = frag;
  } else if (id < 16896) {  // W' realified: [k=2i+p][n=2o+q] per mode
    int id2 = id - 512;
    const float* wsrc = wz;
    size_t off = WS_WZ;
    if (id2 >= 8192) { id2 -= 8192; wsrc = wx; off = WS_WX; }
    int fid = id2 >> 6, m = fid >> 3, kt = (fid >> 2) & 1, nt = fid & 3;
#pragma unroll
    for (int e = 0; e < 8; ++e) {
      int k = kt * 32 + 8 * g + e, i = k >> 1, p = k & 1;
      int n = nt * 16 + r, o = n >> 1, q = n & 1;
      int base = ((i * 32 + o) * 16 + m) * 2;  // raw [i][o][mode][2]
      float re = wsrc[base], im = wsrc[base + 1];
      frag[e] = (half_t)(q ? (p ? re : im) : (p ? -im : re));
    }
    *(f16x8*)(wsh + off + (size_t)id2 * 8) = frag;
  } else if (id < 17152) {  // w1 [32 k][64 n]
    int id2 = id - 16896, nt = id2 >> 6;
#pragma unroll
    for (int e = 0; e < 8; ++e) {
      int k = 8 * g + e, n = nt * 16 + r;
      frag[e] = (half_t)w1[k * 64 + n];
    }
    *(f16x8*)(wsh + WS_W1 + (size_t)id2 * 8) = frag;
  } else if (id < 17408) {  // w2 [64 k][32 n]
    int id2 = id - 17152, fid = id2 >> 6, kt = fid >> 1, nt = fid & 1;
#pragma unroll
    for (int e = 0; e < 8; ++e) {
      int k = kt * 32 + 8 * g + e, n = nt * 16 + r;
      frag[e] = (half_t)w2[k * 32 + n];
    }
    *(f16x8*)(wsh + WS_W2 + (size_t)id2 * 8) = frag;
  }
}

// ====== z-branch: cols = (s1 pair) x (4 consecutive s2); y_z -> d_out slots ======
// block d: b=d>>9, s1base=2*((d>>4)&31), s2base=4*(d&15); col c: s1=s1base+(c>>2),
// s2=s2base+(c&3). Each 128B slot line {s1 pair}x{o} is written by this block only.
__global__ __launch_bounds__(256) void kz(const float* __restrict__ x,
                                          const half_t* __restrict__ wsh,
                                          float* __restrict__ outf) {
  __shared__ __align__(16) char smraw[49152];
  half_t* XB = (half_t*)smraw;            // [256 rows=(c,i)][64 z] swz
  half_t* FB = (half_t*)smraw;            // [16 m][16 c][64 k=2i+p] swz
  half_t* PB = (half_t*)(smraw + 32768);  // [8 c][32 o][32 k=2m+p] swz
  half_t* outh = (half_t*)outf;
  const int t = threadIdx.x, l = t & 63, w = t >> 6, r = l & 15, g = l >> 4;
  const f32x4 vzero = {0.f, 0.f, 0.f, 0.f};

  const int d = blockIdx.x;
  const int bb = d >> 9;
  const int s1base = 2 * ((d >> 4) & 31);
  const int s2base = 4 * (d & 15);
  const int K = s1base >> 1;

  {  // stage x -> XB
    int c = t >> 5, sub = t & 31;
    int i4 = (sub & 7) * 4, zq = sub >> 3;
    int s1c = s1base + (c >> 2), s2c = s2base + (c & 3);
    const float* xp = x + (size_t)((bb * 64 + s1c) * 64 + s2c) * 2048 + i4;
#pragma unroll
    for (int zo = 0; zo < 2; ++zo) {
      int zb = zq * 16 + zo * 8;
      float4 v[8];
#pragma unroll
      for (int zz = 0; zz < 8; ++zz)
        v[zz] = *(const float4*)(xp + (size_t)(zb + zz) * 32);
#pragma unroll
      for (int u = 0; u < 4; ++u) {
        f16x8 rowv;
#pragma unroll
        for (int zz = 0; zz < 8; ++zz) rowv[zz] = (half_t)f4get(v[zz], u);
        int rowi = c * 32 + i4 + u;
        int gr = (zb >> 3) ^ (rowi & 7);
        *(f16x8*)(XB + rowi * 64 + gr * 8) = rowv;
      }
    }
  }
  __syncthreads();

  // forward
  f32x4 fa[2][4];
#pragma unroll
  for (int mt = 0; mt < 2; ++mt)
#pragma unroll
    for (int nt = 0; nt < 4; ++nt) fa[mt][nt] = vzero;
  {
    f16x8 Atf[2][2], Bx[4][2];
#pragma unroll
    for (int mt = 0; mt < 2; ++mt)
#pragma unroll
      for (int kt = 0; kt < 2; ++kt)
        Atf[mt][kt] = *(const f16x8*)(wsh + WS_TF + (size_t)((mt * 2 + kt) * 64 + l) * 8);
#pragma unroll
    for (int nt = 0; nt < 4; ++nt)
#pragma unroll
      for (int kt = 0; kt < 2; ++kt) {
        int rowi = w * 64 + nt * 16 + r;
        int gr = (kt * 4 + g) ^ (rowi & 7);
        Bx[nt][kt] = *(const f16x8*)(XB + rowi * 64 + gr * 8);
      }
#pragma unroll
    for (int kt = 0; kt < 2; ++kt)
#pragma unroll
      for (int nt = 0; nt < 4; ++nt)
#pragma unroll
        for (int mt = 0; mt < 2; ++mt)
          fa[mt][nt] = mfma16(Atf[mt][kt], Bx[nt][kt], fa[mt][nt]);
  }
  __syncthreads();

#pragma unroll
  for (int mt = 0; mt < 2; ++mt)
#pragma unroll
    for (int nt = 0; nt < 4; ++nt)
#pragma unroll
      for (int q = 0; q < 4; ++q) {
        int mc = mt * 16 + 4 * g + q, m = mc >> 1, p = mc & 1;
        int n = w * 64 + nt * 16 + r, c = n >> 5, i = n & 31;
        int k = 2 * i + p;
        FB[(m * 16 + c) * 64 + ((k >> 3) ^ (c & 7)) * 8 + (k & 7)] = (half_t)fa[mt][nt][q];
      }
  __syncthreads();

  // mix
  const half_t* WF = wsh + WS_WZ;
#pragma unroll
  for (int j = 0; j < 4; ++j) {
    int m = w * 4 + j;
    f16x8 Af[2];
#pragma unroll
    for (int kt = 0; kt < 2; ++kt) {
      int gr = (kt * 4 + g) ^ (r & 7);
      Af[kt] = *(const f16x8*)(FB + (m * 16 + r) * 64 + gr * 8);
    }
    f32x4 pa[4];
#pragma unroll
    for (int nt = 0; nt < 4; ++nt) pa[nt] = vzero;
#pragma unroll
    for (int kt = 0; kt < 2; ++kt)
#pragma unroll
      for (int nt = 0; nt < 4; ++nt) {
        f16x8 Bw = *(const f16x8*)(WF + (size_t)((m * 8 + kt * 4 + nt) * 64 + l) * 8);
        pa[nt] = mfma16(Af[kt], Bw, pa[nt]);
      }
#pragma unroll
    for (int nt = 0; nt < 4; ++nt)
#pragma unroll
      for (int q = 0; q < 4; ++q) {
        int c = 4 * g + q;
        if (c < 8) {
          int n = nt * 16 + r, o = n >> 1, q2 = n & 1;
          int k = 2 * m + q2;
          PB[(c * 32 + o) * 32 + ((k >> 3) ^ (o & 3)) * 8 + (k & 7)] = (half_t)pa[nt][q];
        }
      }
  }
  __syncthreads();

  // inverse + store y_z f16 into kx-private d_out slots
  {
    f16x8 Ati[4];
#pragma unroll
    for (int mt = 0; mt < 4; ++mt)
      Ati[mt] = *(const f16x8*)(wsh + WS_TI + (size_t)(mt * 64 + l) * 8);
#pragma unroll
    for (int cc = 0; cc < 2; ++cc) {
      int c = w * 2 + cc;
      int z = c >> 2, s2c = s2base + (c & 3);
      f16x8 Bp[2];
#pragma unroll
      for (int nt = 0; nt < 2; ++nt) {
        int o = nt * 16 + r;
        Bp[nt] = *(const f16x8*)(PB + (c * 32 + o) * 32 + (g ^ (o & 3)) * 8);
      }
      f32x4 ya[4][2];
#pragma unroll
      for (int mt = 0; mt < 4; ++mt)
#pragma unroll
        for (int nt = 0; nt < 2; ++nt) ya[mt][nt] = mfma16(Ati[mt], Bp[nt], vzero);
      const size_t cbase = (size_t)bb * 16777216 + (size_t)s2c * 4096 + z * 32;
#pragma unroll
      for (int mt = 0; mt < 4; ++mt)
#pragma unroll
        for (int nt = 0; nt < 2; ++nt)
#pragma unroll
          for (int q = 0; q < 4; ++q) {
            int s3 = mt * 16 + 4 * g + q, o = nt * 16 + r;
            outh[cbase + (size_t)((s3 & 1) * 32 + K) * 262144 +
                 (size_t)((s3 >> 2) * 4 + ((s3 >> 1) & 1)) * 64 + o] =
                (half_t)ya[mt][nt][q];
          }
    }
  }
}

// ===== x-branch + FFN (round-12 kx structure; yzf via private-slot layout) =====
__global__ __launch_bounds__(256, 4) void kx4(const float* __restrict__ x,
                                              const half_t* __restrict__ wsh,
                                              const float* __restrict__ b1g,
                                              const float* __restrict__ b2g,
                                              float* __restrict__ outf) {
  __shared__ __align__(16) half_t smh[16384];  // 32 KB
  half_t* XB = smh;            // [128 rows=(c*32+i)][64 z]    16KB  [0,8192)
  half_t* FB = smh + 8192;     // [16 m][4 c][64 k=2i+p]        8KB  [8192,12288)
  half_t* PB = smh + 12288;    // [4 c][32 o][32 k=2m+p]        8KB  [12288,16384)
  half_t* YL = smh;            // [256 rows=(c*64+z')][32 o]   16KB  overlays XB (dead)
  half_t* HL = smh + 8192;     // [128 rows][64 n]             16KB  overlays FB+PB (dead)
  const half_t* outh = (const half_t*)outf;
  const int t = threadIdx.x, l = t & 63, w = t >> 6, r = l & 15, g = l >> 4;
  const f32x4 vzero = {0.f, 0.f, 0.f, 0.f};

  const int d = blockIdx.x;
  const int pp = (d & 7) * 512 + (d >> 3);  // XCD-bijective swizzle (4096 = 8*512)
  const int col0 = pp * 4;
  const int b = col0 >> 12, s2 = (col0 >> 6) & 63, s30 = col0 & 63;
  const size_t xbase = (size_t)b * 8388608 + (size_t)s2 * 2048 + (size_t)s30 * 32;

  {  // ---- stage x -> XB (rows = c*32+i, cols = z = s1) ----
    int sub = t & 31, zq = t >> 5;          // zq in [0,8): granule index
    int c = sub >> 3, i4 = (sub & 7) * 4;
    const float* xp = x + xbase + (size_t)c * 32 + i4 + (size_t)(zq * 8) * RSTR;
    float4 v[8];
#pragma unroll
    for (int zz = 0; zz < 8; ++zz) v[zz] = *(const float4*)(xp + (size_t)zz * RSTR);
#pragma unroll
    for (int uu = 0; uu < 4; ++uu) {
      int u = (uu + sub) & 3;               // lane-rotated to spread banks
      f16x8 rowv;
#pragma unroll
      for (int zz = 0; zz < 8; ++zz) rowv[zz] = (half_t)f4get(v[zz], u);
      int rowi = c * 32 + i4 + u;
      *(f16x8*)(XB + rowi * 64 + (zq ^ (rowi & 7)) * 8) = rowv;
    }
  }
  __syncthreads();  // bar1

  // ---- forward: F[32 mc][128 n=(c,i)] = Tf @ X ----
  f32x4 fa[2][2];
  {
    f16x8 Atf[2][2], Bx[2][2];
#pragma unroll
    for (int mt = 0; mt < 2; ++mt)
#pragma unroll
      for (int kt = 0; kt < 2; ++kt)
        Atf[mt][kt] = *(const f16x8*)(wsh + WS_TF + (size_t)((mt * 2 + kt) * 64 + l) * 8);
#pragma unroll
    for (int nt = 0; nt < 2; ++nt)
#pragma unroll
      for (int kt = 0; kt < 2; ++kt) {
        int rowi = w * 32 + nt * 16 + r;
        Bx[nt][kt] = *(const f16x8*)(XB + rowi * 64 + (((kt * 4 + g) ^ (rowi & 7))) * 8);
      }
#pragma unroll
    for (int mt = 0; mt < 2; ++mt)
#pragma unroll
      for (int nt = 0; nt < 2; ++nt) fa[mt][nt] = vzero;
#pragma unroll
    for (int kt = 0; kt < 2; ++kt)
#pragma unroll
      for (int nt = 0; nt < 2; ++nt)
#pragma unroll
        for (int mt = 0; mt < 2; ++mt)
          fa[mt][nt] = mfma16(Atf[mt][kt], Bx[nt][kt], fa[mt][nt]);
  }
  // FB region is disjoint from XB: no barrier needed before writing.
#pragma unroll
  for (int mt = 0; mt < 2; ++mt)
#pragma unroll
    for (int nt = 0; nt < 2; ++nt)
#pragma unroll
      for (int pr = 0; pr < 2; ++pr) {
        int q = 2 * pr;
        int mc = mt * 16 + 4 * g + q, m = mc >> 1;
        int n = w * 32 + nt * 16 + r, c = n >> 5, i = n & 31;
        int k = 2 * i;
        f16x2 pairv = {(half_t)fa[mt][nt][q], (half_t)fa[mt][nt][q + 1]};
        *(f16x2*)(FB + (m * 4 + c) * 64 + (((k >> 3) ^ ((m + 2 * c) & 7))) * 8 + (k & 7)) =
            pairv;
      }
  __syncthreads();  // bar2: FB ready

  // ---- mix: P_m[c][64 (2o+q)] = F_m @ W'_m; A rows r -> F[m][r&3] (bcast) ----
#pragma unroll
  for (int j = 0; j < 4; ++j) {
    int m = w * 4 + j;
    int rsel = r & 3, keym = (m + 2 * rsel) & 7;
    f16x8 Af[2];
#pragma unroll
    for (int kt = 0; kt < 2; ++kt)
      Af[kt] = *(const f16x8*)(FB + (m * 4 + rsel) * 64 + (((kt * 4 + g) ^ keym)) * 8);
    f32x4 pa[4];
#pragma unroll
    for (int nt = 0; nt < 4; ++nt) pa[nt] = vzero;
#pragma unroll
    for (int kt = 0; kt < 2; ++kt)
#pragma unroll
      for (int nt = 0; nt < 4; ++nt) {
        f16x8 Bw = *(const f16x8*)(wsh + WS_WX + (size_t)((m * 8 + kt * 4 + nt) * 64 + l) * 8);
        pa[nt] = mfma16(Af[kt], Bw, pa[nt]);
      }
    if (g == 0) {  // D rows 0..3 = c
#pragma unroll
      for (int nt = 0; nt < 4; ++nt)
#pragma unroll
        for (int q = 0; q < 4; ++q) {
          int c = q;
          int n = nt * 16 + r, o = n >> 1, q2 = n & 1;
          int k = 2 * m + q2;
          PB[(c * 32 + o) * 32 + (((k >> 3) ^ (o & 3))) * 8 + (k & 7)] = (half_t)pa[nt][q];
        }
    }
  }
  __syncthreads();  // bar3: PB ready

  // ---- inverse (c = w): y_x = Ti @ P_c -> YL ----
  // Issue order (in-order vmcnt): Ati first, then yzf/W1F prefetches that
  // drain at bar4 under this phase's compute.
  f16x8 Ati[4];
#pragma unroll
  for (int mt = 0; mt < 4; ++mt)
    Ati[mt] = *(const f16x8*)(wsh + WS_TI + (size_t)(mt * 64 + l) * 8);
  f16x8 Bp[2];
#pragma unroll
  for (int nt = 0; nt < 2; ++nt) {
    int o = nt * 16 + r;
    Bp[nt] = *(const f16x8*)(PB + (w * 32 + o) * 32 + ((g ^ (o & 3))) * 8);
  }
  // yzf for FFN rows rowA = rr*128 + w*32 + mt*16 + r:
  //   s3 = s30 + rr*2 + (w>>1), s1 = (w&1)*32 + mt*16 + r.
  // Private-slot layout: addr = b*16.7M + ((w>>1)*32 + (w&1)*16 + mt*8 + (r>>1))
  //   *262144 + s2*4096 + (s30+rr)*64 + (r&1)*32 + 8g. Lanes (r,g) of one
  //   instruction cover 8 FULL 128B lines.
  f16x8 yzf[2][2];
#pragma unroll
  for (int rr = 0; rr < 2; ++rr)
#pragma unroll
    for (int mt = 0; mt < 2; ++mt) {
      size_t addr = (size_t)b * 16777216 +
                    (size_t)((w >> 1) * 32 + (w & 1) * 16 + mt * 8 + (r >> 1)) * 262144 +
                    (size_t)s2 * 4096 + (size_t)(s30 + rr) * 64 + (r & 1) * 32 + 8 * g;
      yzf[rr][mt] = *(const f16x8*)(outh + addr);
    }
  f16x8 W1F[4];
#pragma unroll
  for (int nt = 0; nt < 4; ++nt)
    W1F[nt] = *(const f16x8*)(wsh + WS_W1 + (size_t)(nt * 64 + l) * 8);
  float b1v[4];
#pragma unroll
  for (int nt = 0; nt < 4; ++nt) b1v[nt] = b1g[nt * 16 + r];
  {
    f32x4 ya[4][2];
#pragma unroll
    for (int mt = 0; mt < 4; ++mt)
#pragma unroll
      for (int nt = 0; nt < 2; ++nt) ya[mt][nt] = mfma16(Ati[mt], Bp[nt], vzero);
#pragma unroll
    for (int mt = 0; mt < 4; ++mt)
#pragma unroll
      for (int nt = 0; nt < 2; ++nt)
#pragma unroll
        for (int q = 0; q < 4; ++q) {
          int zp = mt * 16 + 4 * g + q, o = nt * 16 + r;
          int rowi = w * 64 + zp;
          YL[rowi * 32 + (((o >> 3) ^ ((rowi >> 2) & 3))) * 8 + (o & 7)] =
              (half_t)ya[mt][nt][q];
        }
  }
  __syncthreads();  // bar4: YL ready; yzf/W1F drained; slot reads all done

  // ---- FFN: 2 rounds of 128 rows; HL overlays FB+PB (dead after inverse) ----
  f16x8 W2F[4];
#pragma unroll
  for (int f = 0; f < 4; ++f)
    W2F[f] = *(const f16x8*)(wsh + WS_W2 + (size_t)(f * 64 + l) * 8);
  float b2v[2];
#pragma unroll
  for (int nt = 0; nt < 2; ++nt) b2v[nt] = b2g[nt * 16 + r];

  for (int rr = 0; rr < 2; ++rr) {
    f16x8 AY[2];
#pragma unroll
    for (int mt = 0; mt < 2; ++mt) {
      int rowA = rr * 128 + w * 32 + mt * 16 + r;
      f16x8 ay = *(const f16x8*)(YL + rowA * 32 + ((g ^ ((rowA >> 2) & 3))) * 8);
      AY[mt] = ay + yzf[rr][mt];  // fold z-branch into FFN input (packed f16 adds)
    }
    f32x4 ha[2][4];
#pragma unroll
    for (int mt = 0; mt < 2; ++mt)
#pragma unroll
      for (int nt = 0; nt < 4; ++nt) ha[mt][nt] = mfma16(AY[mt], W1F[nt], vzero);
#pragma unroll
    for (int mt = 0; mt < 2; ++mt)
#pragma unroll
      for (int nt = 0; nt < 4; ++nt)
#pragma unroll
        for (int q = 0; q < 4; ++q) {
          int rloc = w * 32 + mt * 16 + 4 * g + q, n = nt * 16 + r;
          float hv = fmaxf(ha[mt][nt][q] + b1v[nt], 0.f);
          HL[rloc * 64 + (((n >> 3) ^ ((rloc >> 2) & 7))) * 8 + (n & 7)] = (half_t)hv;
        }
    __syncthreads();
    f16x8 AH[2][2];
#pragma unroll
    for (int mt = 0; mt < 2; ++mt)
#pragma unroll
      for (int kt = 0; kt < 2; ++kt) {
        int rowA2 = w * 32 + mt * 16 + r;
        AH[mt][kt] =
            *(const f16x8*)(HL + rowA2 * 64 + (((kt * 4 + g) ^ ((rowA2 >> 2) & 7))) * 8);
      }
    f32x4 oa[2][2];
#pragma unroll
    for (int mt = 0; mt < 2; ++mt)
#pragma unroll
      for (int nt = 0; nt < 2; ++nt) oa[mt][nt] = vzero;
#pragma unroll
    for (int kt = 0; kt < 2; ++kt)
#pragma unroll
      for (int mt = 0; mt < 2; ++mt)
#pragma unroll
        for (int nt = 0; nt < 2; ++nt)
          oa[mt][nt] = mfma16(AH[mt][kt], W2F[kt * 2 + nt], oa[mt][nt]);
#pragma unroll
    for (int mt = 0; mt < 2; ++mt)
#pragma unroll
      for (int nt = 0; nt < 2; ++nt)
#pragma unroll
        for (int q = 0; q < 4; ++q) {
          int rowg = rr * 128 + w * 32 + mt * 16 + 4 * g + q;
          int c = rowg >> 6, zp = rowg & 63, o = nt * 16 + r;
          outf[(size_t)b * 8388608 + (size_t)zp * RSTR + (size_t)s2 * 2048 +
               (size_t)(s30 + c) * 32 + o] = oa[mt][nt][q] + b2v[nt];
        }
    if (rr == 0) __syncthreads();
  }
}

}  // namespace

extern "C" void kernel_launch(void* const* d_in, const int* in_sizes, int n_in,
                              void* d_out, int out_size, void* d_ws, size_t ws_size,
                              hipStream_t stream) {
  const float* x = (const float*)d_in[0];
  const float* wx = (const float*)d_in[1];
  const float* wz = (const float*)d_in[2];
  const float* w1 = (const float*)d_in[3];
  const float* b1 = (const float*)d_in[4];
  const float* w2 = (const float*)d_in[5];
  const float* b2 = (const float*)d_in[6];
  float* out = (float*)d_out;
  half_t* wsh = (half_t*)d_ws;

  hipLaunchKernelGGL(kinit, dim3(68), dim3(256), 0, stream, wx, wz, w1, w2, wsh);
  hipLaunchKernelGGL(kz, dim3(2048), dim3(256), 0, stream, x, wsh, out);
  hipLaunchKernelGGL(kx4, dim3(4096), dim3(256), 0, stream, x, wsh, b1, b2, out);
}